// Round 2
// baseline (476.438 us; speedup 1.0000x reference)
//
#include <hip/hip_runtime.h>

#define N_NODES 50000
#define N_EDGES 600000
#define D 128   // D_IN == HID
#define NCLS 64

// ---------------- CSR build ----------------

__global__ void hist_kernel(const int* __restrict__ dst1, const int* __restrict__ dst2,
                            int* __restrict__ cnt) {
  int i = blockIdx.x * blockDim.x + threadIdx.x;
  if (i < N_EDGES) {
    atomicAdd(&cnt[dst1[i]], 1);
  } else if (i < 2 * N_EDGES) {
    atomicAdd(&cnt[N_NODES + dst2[i - N_EDGES]], 1);
  }
}

#define SCAN_B 1024
__global__ void scan_local(const int* __restrict__ cnt, int* __restrict__ off,
                           int* __restrict__ bsum, int n) {
  __shared__ int sh[SCAN_B];
  int tid = threadIdx.x;
  int gid = blockIdx.x * SCAN_B + tid;
  int v = (gid < n) ? cnt[gid] : 0;
  sh[tid] = v;
  __syncthreads();
  int x = v;
  for (int o = 1; o < SCAN_B; o <<= 1) {
    int y = (tid >= o) ? sh[tid - o] : 0;
    __syncthreads();
    x += y;
    sh[tid] = x;
    __syncthreads();
  }
  if (gid < n) off[gid] = x - v;            // exclusive (pre-carry)
  if (tid == SCAN_B - 1) bsum[blockIdx.x] = x;
}

// parallel block-sum scan (nb <= 128); replaces the old 1-thread serial loop
// (98 dependent global loads ~= 35-40us of pure latency on the critical path)
__global__ void scan_tops(int* __restrict__ bsum, int nb, int* __restrict__ off, int last) {
  __shared__ int sh[128];
  int tid = threadIdx.x;
  int v = (tid < nb) ? bsum[tid] : 0;
  sh[tid] = v;
  __syncthreads();
  int x = v;
  for (int o = 1; o < 128; o <<= 1) {
    int y = (tid >= o) ? sh[tid - o] : 0;
    __syncthreads();
    x += y;
    sh[tid] = x;
    __syncthreads();
  }
  if (tid < nb) bsum[tid] = x - v;   // exclusive block prefix
  if (tid == 127) off[last] = x;     // total == 2E
}

__global__ void scan_add(int* __restrict__ off, int* __restrict__ cur,
                         const int* __restrict__ bsum, int n) {
  int gid = blockIdx.x * SCAN_B + threadIdx.x;
  if (gid < n) {
    int o = off[gid] + bsum[blockIdx.x];
    off[gid] = o;
    cur[gid] = o;
  }
}

__global__ void fill_kernel(const int* __restrict__ src1, const int* __restrict__ dst1,
                            const int* __restrict__ src2, const int* __restrict__ dst2,
                            int* __restrict__ cur, int* __restrict__ adj) {
  int i = blockIdx.x * blockDim.x + threadIdx.x;
  if (i < N_EDGES) {
    int p = atomicAdd(&cur[dst1[i]], 1);
    adj[p] = src1[i];
  } else if (i < 2 * N_EDGES) {
    int e = i - N_EDGES;
    int p = atomicAdd(&cur[N_NODES + dst2[e]], 1);
    adj[p] = src2[e];
  }
}

// ---------------- aggregation: z = 1.7*F + 0.9*sum_g1 F[src] + 0.8*sum_g2 F[src] ----------------
// one wave (64 lanes) per node; lane l owns dims [2l, 2l+1] as float2

__global__ __launch_bounds__(256) void agg_kernel(const float* __restrict__ F,
                                                  const int* __restrict__ off,
                                                  const int* __restrict__ adj,
                                                  float* __restrict__ Z) {
  int wid = (blockIdx.x * blockDim.x + threadIdx.x) >> 6;   // node id
  int lane = threadIdx.x & 63;
  if (wid >= N_NODES) return;
  const float2* __restrict__ F2 = (const float2*)F;
  float2 self = F2[(size_t)wid * 64 + lane];
  float2 acc[2];
#pragma unroll
  for (int g = 0; g < 2; ++g) {
    int row = wid + g * N_NODES;
    int s = off[row], e = off[row + 1];
    float2 a = make_float2(0.f, 0.f);
    for (int base = s; base < e; base += 64) {
      int m = e - base;
      if (m > 64) m = 64;
      int idx = (lane < m) ? adj[base + lane] : 0;  // coalesced index batch
      for (int i = 0; i < m; ++i) {
        int s2 = __shfl(idx, i);                    // register broadcast
        float2 f = F2[(size_t)s2 * 64 + lane];      // 512B/wave coalesced row read
        a.x += f.x;
        a.y += f.y;
      }
    }
    acc[g] = a;
  }
  float2 o;
  o.x = 1.7f * self.x + 0.9f * acc[0].x + 0.8f * acc[1].x;
  o.y = 1.7f * self.y + 0.9f * acc[0].y + 0.8f * acc[1].y;
  ((float2*)Z)[(size_t)wid * 64 + lane] = o;
}

// ---------------- f32 GEMM: C[M,BN] = A[M,128] @ W[128,BN] + bscale*bias ----------------
// block: 256 threads (16x16), tile BM=64 x BN, K fully looped in BK=16 steps

template <int BN>
__global__ __launch_bounds__(256) void gemm_kernel(const float* __restrict__ A,
                                                   const float* __restrict__ W,
                                                   const float* __restrict__ bias, float bscale,
                                                   float* __restrict__ C, int M) {
  constexpr int BM = 64, BK = 16;
  constexpr int TCOL = BN / 16;
  __shared__ float As[BK][BM + 1];
  __shared__ float Ws[BK][BN];
  const int tx = threadIdx.x & 15;
  const int ty = threadIdx.x >> 4;
  const int row0 = blockIdx.x * BM;
  float acc[4][TCOL];
#pragma unroll
  for (int r = 0; r < 4; ++r)
#pragma unroll
    for (int c = 0; c < TCOL; ++c) acc[r][c] = 0.f;

  for (int k0 = 0; k0 < D; k0 += BK) {
    {  // stage A tile (transposed): As[k][row]
      int t = threadIdx.x;
      int r = t >> 2;
      int kq = (t & 3) << 2;
      int gr = row0 + r;
      float4 v = make_float4(0.f, 0.f, 0.f, 0.f);
      if (gr < M) v = *(const float4*)(A + (size_t)gr * D + k0 + kq);
      As[kq + 0][r] = v.x;
      As[kq + 1][r] = v.y;
      As[kq + 2][r] = v.z;
      As[kq + 3][r] = v.w;
    }
    {  // stage W tile: Ws[k][c]
      constexpr int F4 = BN / 4;
#pragma unroll
      for (int it = 0; it < (BK * F4 + 255) / 256; ++it) {
        int idx = threadIdx.x + it * 256;
        if (idx < BK * F4) {
          int k = idx / F4;
          int c = (idx % F4) * 4;
          *(float4*)(&Ws[k][c]) = *(const float4*)(W + (size_t)(k0 + k) * BN + c);
        }
      }
    }
    __syncthreads();
#pragma unroll
    for (int k = 0; k < BK; ++k) {
      float a[4];
#pragma unroll
      for (int r = 0; r < 4; ++r) a[r] = As[k][ty * 4 + r];
      float w[TCOL];
#pragma unroll
      for (int c = 0; c < TCOL; ++c) w[c] = Ws[k][tx * TCOL + c];
#pragma unroll
      for (int r = 0; r < 4; ++r)
#pragma unroll
        for (int c = 0; c < TCOL; ++c) acc[r][c] += a[r] * w[c];
    }
    __syncthreads();
  }
  float bv[TCOL];
#pragma unroll
  for (int c = 0; c < TCOL; ++c) bv[c] = bscale * bias[tx * TCOL + c];
#pragma unroll
  for (int r = 0; r < 4; ++r) {
    int gr = row0 + ty * 4 + r;
    if (gr < M) {
#pragma unroll
      for (int c = 0; c < TCOL; ++c)
        C[(size_t)gr * BN + tx * TCOL + c] = acc[r][c] + bv[c];
    }
  }
}

// ---------------- launch ----------------

extern "C" void kernel_launch(void* const* d_in, const int* in_sizes, int n_in,
                              void* d_out, int out_size, void* d_ws, size_t ws_size,
                              hipStream_t stream) {
  const float* F  = (const float*)d_in[0];
  const int* src1 = (const int*)d_in[1];
  const int* dst1 = (const int*)d_in[2];
  const int* src2 = (const int*)d_in[3];
  const int* dst2 = (const int*)d_in[4];
  const float* W1 = (const float*)d_in[5];
  const float* b1 = (const float*)d_in[6];
  const float* W2 = (const float*)d_in[7];
  const float* b2 = (const float*)d_in[8];
  // d_in[9..16] (gate weights) are mathematically dead: softmax over a size-1
  // axis is identically 1, so every gate scale == 1.0 and only TEM remains.
  float* out = (float*)d_out;

  char* ws = (char*)d_ws;
  auto aln = [](size_t x) { return (x + 255) & ~(size_t)255; };
  size_t o = 0;
  int* cnt_cur = (int*)(ws + o); o = aln(o + (size_t)2 * N_NODES * 4);      // histogram, then fill cursors
  int* off     = (int*)(ws + o); o = aln(o + ((size_t)2 * N_NODES + 1) * 4);
  int* bsum    = (int*)(ws + o); o = aln(o + 256 * 4);
  int* adj     = (int*)(ws + o); o = aln(o + (size_t)2 * N_EDGES * 4);
  float* z     = (float*)(ws + o); o = aln(o + (size_t)N_NODES * D * 4);
  float* x1    = (float*)(ws + o); o = aln(o + (size_t)N_NODES * D * 4);
  (void)ws_size;  // ~57 MB used

  hipMemsetAsync(cnt_cur, 0, (size_t)2 * N_NODES * sizeof(int), stream);
  hist_kernel<<<(2 * N_EDGES + 255) / 256, 256, 0, stream>>>(dst1, dst2, cnt_cur);
  const int NB = (2 * N_NODES + SCAN_B - 1) / SCAN_B;  // 98
  scan_local<<<NB, SCAN_B, 0, stream>>>(cnt_cur, off, bsum, 2 * N_NODES);
  scan_tops<<<1, 128, 0, stream>>>(bsum, NB, off, 2 * N_NODES);
  scan_add<<<NB, SCAN_B, 0, stream>>>(off, cnt_cur, bsum, 2 * N_NODES);
  fill_kernel<<<(2 * N_EDGES + 255) / 256, 256, 0, stream>>>(src1, dst1, src2, dst2, cnt_cur, adj);

  // layer 1: z = 1.7F + 0.9*agg1(F) + 0.8*agg2(F);  x1 = z @ W1 + 1.7*b1
  agg_kernel<<<N_NODES / 4, 256, 0, stream>>>(F, off, adj, z);
  gemm_kernel<128><<<(N_NODES + 63) / 64, 256, 0, stream>>>(z, W1, b1, 1.7f, x1, N_NODES);
  // layer 2: z2 = 1.7x1 + 0.9*agg1(x1) + 0.8*agg2(x1);  out = z2 @ W2 + 1.7*b2
  agg_kernel<<<N_NODES / 4, 256, 0, stream>>>(x1, off, adj, z);
  gemm_kernel<64><<<(N_NODES + 63) / 64, 256, 0, stream>>>(z, W2, b2, 1.7f, out, N_NODES);
}

// Round 5
// 413.343 us; speedup vs baseline: 1.1526x; 1.1526x over previous
//
#include <hip/hip_runtime.h>

#define N_NODES 50000
#define N_EDGES 600000
#define D 128   // D_IN == HID
#define NCLS 64

// ============ CSR build (bucket edges by dst; both graphs concatenated) ============
// (validated: identical to the Round-1 source that passed with absmax 0.25)

__global__ void hist_kernel(const int* __restrict__ dst1, const int* __restrict__ dst2,
                            int* __restrict__ cnt) {
  int i = blockIdx.x * blockDim.x + threadIdx.x;
  if (i < N_EDGES) {
    atomicAdd(&cnt[dst1[i]], 1);
  } else if (i < 2 * N_EDGES) {
    atomicAdd(&cnt[N_NODES + dst2[i - N_EDGES]], 1);
  }
}

#define SCAN_B 1024
__global__ void scan_local(const int* __restrict__ cnt, int* __restrict__ off,
                           int* __restrict__ bsum, int n) {
  __shared__ int sh[SCAN_B];
  int tid = threadIdx.x;
  int gid = blockIdx.x * SCAN_B + tid;
  int v = (gid < n) ? cnt[gid] : 0;
  sh[tid] = v;
  __syncthreads();
  int x = v;
  for (int o = 1; o < SCAN_B; o <<= 1) {
    int y = (tid >= o) ? sh[tid - o] : 0;
    __syncthreads();
    x += y;
    sh[tid] = x;
    __syncthreads();
  }
  if (gid < n) off[gid] = x - v;            // exclusive (pre-carry)
  if (tid == SCAN_B - 1) bsum[blockIdx.x] = x;
}

__global__ void scan_tops(int* __restrict__ bsum, int nb, int* __restrict__ off, int last) {
  __shared__ int sh[128];
  int tid = threadIdx.x;
  int v = (tid < nb) ? bsum[tid] : 0;
  sh[tid] = v;
  __syncthreads();
  int x = v;
  for (int o = 1; o < 128; o <<= 1) {
    int y = (tid >= o) ? sh[tid - o] : 0;
    __syncthreads();
    x += y;
    sh[tid] = x;
    __syncthreads();
  }
  if (tid < nb) bsum[tid] = x - v;   // exclusive block prefix
  if (tid == 127) off[last] = x;     // total == 2E
}

__global__ void scan_add(int* __restrict__ off, int* __restrict__ cur,
                         const int* __restrict__ bsum, int n) {
  int gid = blockIdx.x * SCAN_B + threadIdx.x;
  if (gid < n) {
    int o = off[gid] + bsum[blockIdx.x];
    off[gid] = o;
    cur[gid] = o;
  }
}

__global__ void fill_kernel(const int* __restrict__ src1, const int* __restrict__ dst1,
                            const int* __restrict__ src2, const int* __restrict__ dst2,
                            int* __restrict__ cur, int* __restrict__ adj) {
  int i = blockIdx.x * blockDim.x + threadIdx.x;
  if (i < N_EDGES) {
    int p = atomicAdd(&cur[dst1[i]], 1);
    adj[p] = src1[i];
  } else if (i < 2 * N_EDGES) {
    int e = i - N_EDGES;
    int p = atomicAdd(&cur[N_NODES + dst2[e]], 1);
    adj[p] = src2[e];
  }
}

// ============ micro-GEMM: W12 = W1@W2 (128x64), c = b1@W2 (64) ============

__global__ void w12_kernel(const float* __restrict__ W1, const float* __restrict__ W2,
                           const float* __restrict__ b1,
                           float* __restrict__ W12, float* __restrict__ c) {
  int o = blockIdx.x * blockDim.x + threadIdx.x;  // 0..8191
  int i = o >> 6, j = o & 63;
  float s = 0.f;
  for (int k = 0; k < D; ++k) s += W1[i * D + k] * W2[k * NCLS + j];
  W12[i * NCLS + j] = s;
  if (o < NCLS) {
    float t = 0.f;
    for (int k = 0; k < D; ++k) t += b1[k] * W2[k * NCLS + o];
    c[o] = t;
  }
}

// ============ GEMM: C[M,64] = A[M,128] @ W[128,64] (no bias) ============
// (structurally identical to the validated gemm_kernel<64>, bias removed)

__global__ __launch_bounds__(256) void gemm64_kernel(const float* __restrict__ A,
                                                     const float* __restrict__ W,
                                                     float* __restrict__ C, int M) {
  constexpr int BM = 64, BK = 16, BN = 64;
  constexpr int TCOL = BN / 16;  // 4
  __shared__ float As[BK][BM + 1];
  __shared__ float Ws[BK][BN];
  const int tx = threadIdx.x & 15;
  const int ty = threadIdx.x >> 4;
  const int row0 = blockIdx.x * BM;
  float acc[4][TCOL];
#pragma unroll
  for (int r = 0; r < 4; ++r)
#pragma unroll
    for (int c = 0; c < TCOL; ++c) acc[r][c] = 0.f;

  for (int k0 = 0; k0 < D; k0 += BK) {
    {  // stage A tile transposed: As[k][row]
      int t = threadIdx.x;
      int r = t >> 2;
      int kq = (t & 3) << 2;
      int gr = row0 + r;
      float4 v = make_float4(0.f, 0.f, 0.f, 0.f);
      if (gr < M) v = *(const float4*)(A + (size_t)gr * D + k0 + kq);
      As[kq + 0][r] = v.x;
      As[kq + 1][r] = v.y;
      As[kq + 2][r] = v.z;
      As[kq + 3][r] = v.w;
    }
    {  // stage W tile: Ws[k][c]  (16*16 float4 = 256 threads, one each)
      int k = threadIdx.x >> 4;
      int c4 = (threadIdx.x & 15) << 2;
      *(float4*)(&Ws[k][c4]) = *(const float4*)(W + (size_t)(k0 + k) * BN + c4);
    }
    __syncthreads();
#pragma unroll
    for (int k = 0; k < BK; ++k) {
      float a[4];
#pragma unroll
      for (int r = 0; r < 4; ++r) a[r] = As[k][ty * 4 + r];
      float w[TCOL];
#pragma unroll
      for (int c = 0; c < TCOL; ++c) w[c] = Ws[k][tx * TCOL + c];
#pragma unroll
      for (int r = 0; r < 4; ++r)
#pragma unroll
        for (int c = 0; c < TCOL; ++c) acc[r][c] += a[r] * w[c];
    }
    __syncthreads();
  }
#pragma unroll
  for (int r = 0; r < 4; ++r) {
    int gr = row0 + ty * 4 + r;
    if (gr < M) {
#pragma unroll
      for (int c = 0; c < TCOL; ++c)
        C[(size_t)gr * BN + tx * TCOL + c] = acc[r][c];
    }
  }
}

// ============ 64-wide aggregation: Y = 1.7X + 0.9*A1(X) + 0.8*A2(X) [+ epilogue] ============
// BISECT version: verbatim generalization of the HW-validated Round-1 agg pattern.
// One wave per node; lane l owns column l (scalar). Edge indices loaded in
// coalesced 64-batches, uniform-trip __shfl broadcast. No lane groups, no butterfly.
// FIN: Y += 1.7*s(v)*c + 1.7*b2, s(v) = 1.7 + 0.9*deg1 + 0.8*deg2.

template <int FIN>
__global__ __launch_bounds__(256) void agg64_kernel(const float* __restrict__ X,
                                                    const int* __restrict__ off,
                                                    const int* __restrict__ adj,
                                                    const float* __restrict__ cvec,
                                                    const float* __restrict__ b2,
                                                    float* __restrict__ Y) {
  int wid = (blockIdx.x * blockDim.x + threadIdx.x) >> 6;  // node
  if (wid >= N_NODES) return;
  int lane = threadIdx.x & 63;

  float self = X[(size_t)wid * 64 + lane];

  int s1 = off[wid], e1 = off[wid + 1];
  int s2 = off[N_NODES + wid], e2 = off[N_NODES + wid + 1];

  float acc[2];
#pragma unroll
  for (int g = 0; g < 2; ++g) {
    int s = g ? s2 : s1, e = g ? e2 : e1;
    float a = 0.f;
    for (int base = s; base < e; base += 64) {
      int m = e - base;
      if (m > 64) m = 64;
      int idx = (lane < m) ? adj[base + lane] : 0;  // coalesced index batch
      for (int i = 0; i < m; ++i) {
        int n = __shfl(idx, i);                     // wave-uniform broadcast
        a += X[(size_t)n * 64 + lane];              // 256B coalesced row read
      }
    }
    acc[g] = a;
  }
  float y = 1.7f * self + 0.9f * acc[0] + 0.8f * acc[1];
  if (FIN) {
    float sv = 1.7f * (1.7f + 0.9f * (float)(e1 - s1) + 0.8f * (float)(e2 - s2));
    y += sv * cvec[lane] + 1.7f * b2[lane];
  }
  Y[(size_t)wid * 64 + lane] = y;
}

// ============ launch ============
// Math: gates == 1 (softmax over size-1 axis), so with L(X) = 1.7X + 0.9*A1X + 0.8*A2X:
//   out = L(L(F)) @ (W1@W2) + 1.7*s(v)*(b1@W2) + 1.7*b2
//       = L(L(F @ W12)) + 1.7*s(v)*c + 1.7*b2          (agg commutes with @W, exactly)
// -> all gathers are 64-wide instead of 128-wide, and the N*128*128 GEMM dies.

extern "C" void kernel_launch(void* const* d_in, const int* in_sizes, int n_in,
                              void* d_out, int out_size, void* d_ws, size_t ws_size,
                              hipStream_t stream) {
  const float* F  = (const float*)d_in[0];
  const int* src1 = (const int*)d_in[1];
  const int* dst1 = (const int*)d_in[2];
  const int* src2 = (const int*)d_in[3];
  const int* dst2 = (const int*)d_in[4];
  const float* W1 = (const float*)d_in[5];
  const float* b1 = (const float*)d_in[6];
  const float* W2 = (const float*)d_in[7];
  const float* b2 = (const float*)d_in[8];
  // d_in[9..16] (gate weights) are dead: softmax over a size-1 axis == 1.
  float* out = (float*)d_out;

  char* ws = (char*)d_ws;
  auto aln = [](size_t x) { return (x + 255) & ~(size_t)255; };
  size_t o = 0;
  int* cnt_cur = (int*)(ws + o); o = aln(o + (size_t)2 * N_NODES * 4);
  int* off     = (int*)(ws + o); o = aln(o + ((size_t)2 * N_NODES + 1) * 4);
  int* bsum    = (int*)(ws + o); o = aln(o + 256 * 4);
  int* adj     = (int*)(ws + o); o = aln(o + (size_t)2 * N_EDGES * 4);
  float* W12   = (float*)(ws + o); o = aln(o + (size_t)D * NCLS * 4);
  float* cvec  = (float*)(ws + o); o = aln(o + NCLS * 4);
  float* H     = (float*)(ws + o); o = aln(o + (size_t)N_NODES * NCLS * 4);
  float* T     = (float*)(ws + o); o = aln(o + (size_t)N_NODES * NCLS * 4);
  (void)ws_size;  // ~31 MB used

  // CSR build
  hipMemsetAsync(cnt_cur, 0, (size_t)2 * N_NODES * sizeof(int), stream);
  hist_kernel<<<(2 * N_EDGES + 255) / 256, 256, 0, stream>>>(dst1, dst2, cnt_cur);
  const int NB = (2 * N_NODES + SCAN_B - 1) / SCAN_B;  // 98
  scan_local<<<NB, SCAN_B, 0, stream>>>(cnt_cur, off, bsum, 2 * N_NODES);
  scan_tops<<<1, 128, 0, stream>>>(bsum, NB, off, 2 * N_NODES);
  scan_add<<<NB, SCAN_B, 0, stream>>>(off, cnt_cur, bsum, 2 * N_NODES);
  fill_kernel<<<(2 * N_EDGES + 255) / 256, 256, 0, stream>>>(src1, dst1, src2, dst2, cnt_cur, adj);

  // weights: W12 = W1@W2, c = b1@W2
  w12_kernel<<<32, 256, 0, stream>>>(W1, W2, b1, W12, cvec);
  // H = F @ W12
  gemm64_kernel<<<(N_NODES + 63) / 64, 256, 0, stream>>>(F, W12, H, N_NODES);
  // T = L(H)
  agg64_kernel<0><<<N_NODES / 4, 256, 0, stream>>>(H, off, adj, cvec, b2, T);
  // out = L(T) + 1.7*s(v)*c + 1.7*b2
  agg64_kernel<1><<<N_NODES / 4, 256, 0, stream>>>(T, off, adj, cvec, b2, out);
}

// Round 6
// 408.111 us; speedup vs baseline: 1.1674x; 1.0128x over previous
//
#include <hip/hip_runtime.h>

#define N_NODES 50000
#define N_EDGES 600000
#define D 128   // D_IN == HID
#define NCLS 64

// bf16 helpers (tables only; all arithmetic stays f32)
__device__ inline unsigned short f2bf(float f) {
  unsigned int u = __float_as_uint(f);
  unsigned int r = (u + 0x7FFF + ((u >> 16) & 1)) >> 16;  // RNE
  return (unsigned short)r;
}
__device__ inline float bf2f(unsigned short b) {
  return __uint_as_float(((unsigned int)b) << 16);
}

// ============ CSR build (bucket edges by dst; both graphs concatenated) ============
// (HW-validated; untouched this round — control for fill_kernel's 88 us)

__global__ void hist_kernel(const int* __restrict__ dst1, const int* __restrict__ dst2,
                            int* __restrict__ cnt) {
  int i = blockIdx.x * blockDim.x + threadIdx.x;
  if (i < N_EDGES) {
    atomicAdd(&cnt[dst1[i]], 1);
  } else if (i < 2 * N_EDGES) {
    atomicAdd(&cnt[N_NODES + dst2[i - N_EDGES]], 1);
  }
}

#define SCAN_B 1024
__global__ void scan_local(const int* __restrict__ cnt, int* __restrict__ off,
                           int* __restrict__ bsum, int n) {
  __shared__ int sh[SCAN_B];
  int tid = threadIdx.x;
  int gid = blockIdx.x * SCAN_B + tid;
  int v = (gid < n) ? cnt[gid] : 0;
  sh[tid] = v;
  __syncthreads();
  int x = v;
  for (int o = 1; o < SCAN_B; o <<= 1) {
    int y = (tid >= o) ? sh[tid - o] : 0;
    __syncthreads();
    x += y;
    sh[tid] = x;
    __syncthreads();
  }
  if (gid < n) off[gid] = x - v;            // exclusive (pre-carry)
  if (tid == SCAN_B - 1) bsum[blockIdx.x] = x;
}

__global__ void scan_tops(int* __restrict__ bsum, int nb, int* __restrict__ off, int last) {
  __shared__ int sh[128];
  int tid = threadIdx.x;
  int v = (tid < nb) ? bsum[tid] : 0;
  sh[tid] = v;
  __syncthreads();
  int x = v;
  for (int o = 1; o < 128; o <<= 1) {
    int y = (tid >= o) ? sh[tid - o] : 0;
    __syncthreads();
    x += y;
    sh[tid] = x;
    __syncthreads();
  }
  if (tid < nb) bsum[tid] = x - v;   // exclusive block prefix
  if (tid == 127) off[last] = x;     // total == 2E
}

__global__ void scan_add(int* __restrict__ off, int* __restrict__ cur,
                         const int* __restrict__ bsum, int n) {
  int gid = blockIdx.x * SCAN_B + threadIdx.x;
  if (gid < n) {
    int o = off[gid] + bsum[blockIdx.x];
    off[gid] = o;
    cur[gid] = o;
  }
}

__global__ void fill_kernel(const int* __restrict__ src1, const int* __restrict__ dst1,
                            const int* __restrict__ src2, const int* __restrict__ dst2,
                            int* __restrict__ cur, int* __restrict__ adj) {
  int i = blockIdx.x * blockDim.x + threadIdx.x;
  if (i < N_EDGES) {
    int p = atomicAdd(&cur[dst1[i]], 1);
    adj[p] = src1[i];
  } else if (i < 2 * N_EDGES) {
    int e = i - N_EDGES;
    int p = atomicAdd(&cur[N_NODES + dst2[e]], 1);
    adj[p] = src2[e];
  }
}

// ============ micro-GEMM: W12 = W1@W2 (128x64), c = b1@W2 (64) ============

__global__ void w12_kernel(const float* __restrict__ W1, const float* __restrict__ W2,
                           const float* __restrict__ b1,
                           float* __restrict__ W12, float* __restrict__ c) {
  int o = blockIdx.x * blockDim.x + threadIdx.x;  // 0..8191
  int i = o >> 6, j = o & 63;
  float s = 0.f;
  for (int k = 0; k < D; ++k) s += W1[i * D + k] * W2[k * NCLS + j];
  W12[i * NCLS + j] = s;
  if (o < NCLS) {
    float t = 0.f;
    for (int k = 0; k < D; ++k) t += b1[k] * W2[k * NCLS + o];
    c[o] = t;
  }
}

// ============ GEMM: H[M,64] = A[M,128] @ W[128,64], output stored as bf16 ============

__global__ __launch_bounds__(256) void gemm64_kernel(const float* __restrict__ A,
                                                     const float* __restrict__ W,
                                                     unsigned short* __restrict__ C, int M) {
  constexpr int BM = 64, BK = 16, BN = 64;
  constexpr int TCOL = BN / 16;  // 4
  __shared__ float As[BK][BM + 1];
  __shared__ float Ws[BK][BN];
  const int tx = threadIdx.x & 15;
  const int ty = threadIdx.x >> 4;
  const int row0 = blockIdx.x * BM;
  float acc[4][TCOL];
#pragma unroll
  for (int r = 0; r < 4; ++r)
#pragma unroll
    for (int c = 0; c < TCOL; ++c) acc[r][c] = 0.f;

  for (int k0 = 0; k0 < D; k0 += BK) {
    {  // stage A tile transposed: As[k][row]
      int t = threadIdx.x;
      int r = t >> 2;
      int kq = (t & 3) << 2;
      int gr = row0 + r;
      float4 v = make_float4(0.f, 0.f, 0.f, 0.f);
      if (gr < M) v = *(const float4*)(A + (size_t)gr * D + k0 + kq);
      As[kq + 0][r] = v.x;
      As[kq + 1][r] = v.y;
      As[kq + 2][r] = v.z;
      As[kq + 3][r] = v.w;
    }
    {  // stage W tile: Ws[k][c]  (16*16 float4 = 256 threads, one each)
      int k = threadIdx.x >> 4;
      int c4 = (threadIdx.x & 15) << 2;
      *(float4*)(&Ws[k][c4]) = *(const float4*)(W + (size_t)(k0 + k) * BN + c4);
    }
    __syncthreads();
#pragma unroll
    for (int k = 0; k < BK; ++k) {
      float a[4];
#pragma unroll
      for (int r = 0; r < 4; ++r) a[r] = As[k][ty * 4 + r];
      float w[TCOL];
#pragma unroll
      for (int c = 0; c < TCOL; ++c) w[c] = Ws[k][tx * TCOL + c];
#pragma unroll
      for (int r = 0; r < 4; ++r)
#pragma unroll
        for (int c = 0; c < TCOL; ++c) acc[r][c] += a[r] * w[c];
    }
    __syncthreads();
  }
#pragma unroll
  for (int r = 0; r < 4; ++r) {
    int gr = row0 + ty * 4 + r;
    if (gr < M) {
      ushort4 pk;
      pk.x = f2bf(acc[r][0]);
      pk.y = f2bf(acc[r][1]);
      pk.z = f2bf(acc[r][2]);
      pk.w = f2bf(acc[r][3]);
      *(ushort4*)(C + (size_t)gr * BN + tx * TCOL) = pk;  // 8B coalesced store
    }
  }
}

// ============ 64-wide aggregation over bf16 table: Y = 1.7X + 0.9*A1(X) + 0.8*A2(X) ============
// Validated access pattern (one wave/node, lane = column, uniform-trip __shfl
// broadcast), narrowed to 2B/lane gathers. Accumulation in f32.
// OUT_BF16: write Y as bf16 (layer-1 -> feeds next gather); else f32 (final out).
// FIN: Y += 1.7*s(v)*c + 1.7*b2, s(v) = 1.7 + 0.9*deg1 + 0.8*deg2.

template <int FIN, int OUT_BF16>
__global__ __launch_bounds__(256) void agg64_kernel(const unsigned short* __restrict__ X,
                                                    const int* __restrict__ off,
                                                    const int* __restrict__ adj,
                                                    const float* __restrict__ cvec,
                                                    const float* __restrict__ b2,
                                                    void* __restrict__ Yv) {
  int wid = (blockIdx.x * blockDim.x + threadIdx.x) >> 6;  // node
  if (wid >= N_NODES) return;
  int lane = threadIdx.x & 63;

  float self = bf2f(X[(size_t)wid * 64 + lane]);

  int s1 = off[wid], e1 = off[wid + 1];
  int s2 = off[N_NODES + wid], e2 = off[N_NODES + wid + 1];

  float acc[2];
#pragma unroll
  for (int g = 0; g < 2; ++g) {
    int s = g ? s2 : s1, e = g ? e2 : e1;
    float a = 0.f;
    for (int base = s; base < e; base += 64) {
      int m = e - base;
      if (m > 64) m = 64;
      int idx = (lane < m) ? adj[base + lane] : 0;  // coalesced index batch
      for (int i = 0; i < m; ++i) {
        int n = __shfl(idx, i);                     // wave-uniform broadcast
        a += bf2f(X[(size_t)n * 64 + lane]);        // 128B coalesced row read
      }
    }
    acc[g] = a;
  }
  float y = 1.7f * self + 0.9f * acc[0] + 0.8f * acc[1];
  if (FIN) {
    float sv = 1.7f * (1.7f + 0.9f * (float)(e1 - s1) + 0.8f * (float)(e2 - s2));
    y += sv * cvec[lane] + 1.7f * b2[lane];
  }
  if (OUT_BF16) {
    ((unsigned short*)Yv)[(size_t)wid * 64 + lane] = f2bf(y);
  } else {
    ((float*)Yv)[(size_t)wid * 64 + lane] = y;
  }
}

// ============ launch ============
// Math: gates == 1 (softmax over size-1 axis), so with L(X) = 1.7X + 0.9*A1X + 0.8*A2X:
//   out = L(L(F)) @ (W1@W2) + 1.7*s(v)*(b1@W2) + 1.7*b2
//       = L(L(F @ W12)) + 1.7*s(v)*c + 1.7*b2          (agg commutes with @W, exactly)
// Gather tables H,T held in bf16 (halves gather bytes; f32 accumulate).

extern "C" void kernel_launch(void* const* d_in, const int* in_sizes, int n_in,
                              void* d_out, int out_size, void* d_ws, size_t ws_size,
                              hipStream_t stream) {
  const float* F  = (const float*)d_in[0];
  const int* src1 = (const int*)d_in[1];
  const int* dst1 = (const int*)d_in[2];
  const int* src2 = (const int*)d_in[3];
  const int* dst2 = (const int*)d_in[4];
  const float* W1 = (const float*)d_in[5];
  const float* b1 = (const float*)d_in[6];
  const float* W2 = (const float*)d_in[7];
  const float* b2 = (const float*)d_in[8];
  // d_in[9..16] (gate weights) are dead: softmax over a size-1 axis == 1.
  float* out = (float*)d_out;

  char* ws = (char*)d_ws;
  auto aln = [](size_t x) { return (x + 255) & ~(size_t)255; };
  size_t o = 0;
  int* cnt_cur = (int*)(ws + o); o = aln(o + (size_t)2 * N_NODES * 4);
  int* off     = (int*)(ws + o); o = aln(o + ((size_t)2 * N_NODES + 1) * 4);
  int* bsum    = (int*)(ws + o); o = aln(o + 256 * 4);
  int* adj     = (int*)(ws + o); o = aln(o + (size_t)2 * N_EDGES * 4);
  float* W12   = (float*)(ws + o); o = aln(o + (size_t)D * NCLS * 4);
  float* cvec  = (float*)(ws + o); o = aln(o + NCLS * 4);
  unsigned short* H = (unsigned short*)(ws + o); o = aln(o + (size_t)N_NODES * NCLS * 2);
  unsigned short* T = (unsigned short*)(ws + o); o = aln(o + (size_t)N_NODES * NCLS * 2);
  (void)ws_size;  // ~25 MB used

  // CSR build
  hipMemsetAsync(cnt_cur, 0, (size_t)2 * N_NODES * sizeof(int), stream);
  hist_kernel<<<(2 * N_EDGES + 255) / 256, 256, 0, stream>>>(dst1, dst2, cnt_cur);
  const int NB = (2 * N_NODES + SCAN_B - 1) / SCAN_B;  // 98
  scan_local<<<NB, SCAN_B, 0, stream>>>(cnt_cur, off, bsum, 2 * N_NODES);
  scan_tops<<<1, 128, 0, stream>>>(bsum, NB, off, 2 * N_NODES);
  scan_add<<<NB, SCAN_B, 0, stream>>>(off, cnt_cur, bsum, 2 * N_NODES);
  fill_kernel<<<(2 * N_EDGES + 255) / 256, 256, 0, stream>>>(src1, dst1, src2, dst2, cnt_cur, adj);

  // weights: W12 = W1@W2, c = b1@W2
  w12_kernel<<<32, 256, 0, stream>>>(W1, W2, b1, W12, cvec);
  // H = bf16(F @ W12)
  gemm64_kernel<<<(N_NODES + 63) / 64, 256, 0, stream>>>(F, W12, H, N_NODES);
  // T = bf16(L(H))
  agg64_kernel<0, 1><<<N_NODES / 4, 256, 0, stream>>>(H, off, adj, cvec, b2, T);
  // out = L(T) + 1.7*s(v)*c + 1.7*b2   (f32)
  agg64_kernel<1, 0><<<N_NODES / 4, 256, 0, stream>>>(T, off, adj, cvec, b2, out);
}

// Round 7
// 308.729 us; speedup vs baseline: 1.5432x; 1.3219x over previous
//
#include <hip/hip_runtime.h>

#define N_NODES 50000
#define N_EDGES 600000
#define D 128   // D_IN == HID
#define NCLS 64

// Binned CSR build: rows 0..2N-1 (graph1 then graph2), 128 rows/bin
#define NBINS 782        // ceil(100000/128)
#define BIN_CAP 2048     // mean 1536, sd 39 -> +13 sigma
#define BCNT_STRIDE 16   // one cache line per bin counter

// bf16 helpers (tables only; all arithmetic stays f32)
__device__ inline unsigned short f2bf(float f) {
  unsigned int u = __float_as_uint(f);
  unsigned int r = (u + 0x7FFF + ((u >> 16) & 1)) >> 16;  // RNE
  return (unsigned short)r;
}
__device__ inline float bf2f(unsigned short b) {
  return __uint_as_float(((unsigned int)b) << 16);
}

// ============ pass 1: scatter (row,src) pairs into 128-row bins ============

__global__ void bin_scatter(const int* __restrict__ src1, const int* __restrict__ dst1,
                            const int* __restrict__ src2, const int* __restrict__ dst2,
                            int* __restrict__ bincnt, int2* __restrict__ binbuf) {
  int i = blockIdx.x * blockDim.x + threadIdx.x;
  int row, src;
  if (i < N_EDGES) {
    row = dst1[i];            src = src1[i];
  } else if (i < 2 * N_EDGES) {
    int e = i - N_EDGES;
    row = N_NODES + dst2[e];  src = src2[e];
  } else {
    return;
  }
  int b = row >> 7;
  int p = atomicAdd(&bincnt[b * BCNT_STRIDE], 1);
  if (p < BIN_CAP) binbuf[(size_t)b * BIN_CAP + p] = make_int2(row, src);
}

// ============ per-bin histogram via LDS (replaces global random-atomic hist) ============

__global__ __launch_bounds__(256) void bin_hist(const int* __restrict__ bincnt,
                                                const int2* __restrict__ binbuf,
                                                int* __restrict__ cnt) {
  __shared__ int lc[128];
  int b = blockIdx.x;
  if (threadIdx.x < 128) lc[threadIdx.x] = 0;
  __syncthreads();
  int n = min(bincnt[b * BCNT_STRIDE], BIN_CAP);
  for (int t = threadIdx.x; t < n; t += 256) {
    int row = binbuf[(size_t)b * BIN_CAP + t].x;
    atomicAdd(&lc[row & 127], 1);
  }
  __syncthreads();
  if (threadIdx.x < 128) {
    int row = (b << 7) + threadIdx.x;
    if (row < 2 * N_NODES) cnt[row] = lc[threadIdx.x];
  }
}

// ============ scans (unchanged, HW-validated) ============

#define SCAN_B 1024
__global__ void scan_local(const int* __restrict__ cnt, int* __restrict__ off,
                           int* __restrict__ bsum, int n) {
  __shared__ int sh[SCAN_B];
  int tid = threadIdx.x;
  int gid = blockIdx.x * SCAN_B + tid;
  int v = (gid < n) ? cnt[gid] : 0;
  sh[tid] = v;
  __syncthreads();
  int x = v;
  for (int o = 1; o < SCAN_B; o <<= 1) {
    int y = (tid >= o) ? sh[tid - o] : 0;
    __syncthreads();
    x += y;
    sh[tid] = x;
    __syncthreads();
  }
  if (gid < n) off[gid] = x - v;            // exclusive (pre-carry)
  if (tid == SCAN_B - 1) bsum[blockIdx.x] = x;
}

__global__ void scan_tops(int* __restrict__ bsum, int nb, int* __restrict__ off, int last) {
  __shared__ int sh[128];
  int tid = threadIdx.x;
  int v = (tid < nb) ? bsum[tid] : 0;
  sh[tid] = v;
  __syncthreads();
  int x = v;
  for (int o = 1; o < 128; o <<= 1) {
    int y = (tid >= o) ? sh[tid - o] : 0;
    __syncthreads();
    x += y;
    sh[tid] = x;
    __syncthreads();
  }
  if (tid < nb) bsum[tid] = x - v;   // exclusive block prefix
  if (tid == 127) off[last] = x;     // total == 2E
}

__global__ void scan_add(int* __restrict__ off, int* __restrict__ cur,
                         const int* __restrict__ bsum, int n) {
  int gid = blockIdx.x * SCAN_B + threadIdx.x;
  if (gid < n) {
    int o = off[gid] + bsum[blockIdx.x];
    off[gid] = o;
    cur[gid] = o;
  }
}

// ============ pass 2: bin-local fill (adj writes land in ~6KB contiguous range) ============

__global__ __launch_bounds__(256) void bin_fill(const int* __restrict__ bincnt,
                                                const int2* __restrict__ binbuf,
                                                int* __restrict__ cur, int* __restrict__ adj) {
  int b = blockIdx.x;
  int n = min(bincnt[b * BCNT_STRIDE], BIN_CAP);
  for (int t = threadIdx.x; t < n; t += 256) {
    int2 e = binbuf[(size_t)b * BIN_CAP + t];
    int p = atomicAdd(&cur[e.x], 1);
    adj[p] = e.y;
  }
}

// ============ micro-GEMM: W12 = W1@W2 (128x64), c = b1@W2 (64) ============

__global__ void w12_kernel(const float* __restrict__ W1, const float* __restrict__ W2,
                           const float* __restrict__ b1,
                           float* __restrict__ W12, float* __restrict__ c) {
  int o = blockIdx.x * blockDim.x + threadIdx.x;  // 0..8191
  int i = o >> 6, j = o & 63;
  float s = 0.f;
  for (int k = 0; k < D; ++k) s += W1[i * D + k] * W2[k * NCLS + j];
  W12[i * NCLS + j] = s;
  if (o < NCLS) {
    float t = 0.f;
    for (int k = 0; k < D; ++k) t += b1[k] * W2[k * NCLS + o];
    c[o] = t;
  }
}

// ============ GEMM: H[M,64] = A[M,128] @ W[128,64], output stored as bf16 ============

__global__ __launch_bounds__(256) void gemm64_kernel(const float* __restrict__ A,
                                                     const float* __restrict__ W,
                                                     unsigned short* __restrict__ C, int M) {
  constexpr int BM = 64, BK = 16, BN = 64;
  constexpr int TCOL = BN / 16;  // 4
  __shared__ float As[BK][BM + 1];
  __shared__ float Ws[BK][BN];
  const int tx = threadIdx.x & 15;
  const int ty = threadIdx.x >> 4;
  const int row0 = blockIdx.x * BM;
  float acc[4][TCOL];
#pragma unroll
  for (int r = 0; r < 4; ++r)
#pragma unroll
    for (int c = 0; c < TCOL; ++c) acc[r][c] = 0.f;

  for (int k0 = 0; k0 < D; k0 += BK) {
    {  // stage A tile transposed: As[k][row]
      int t = threadIdx.x;
      int r = t >> 2;
      int kq = (t & 3) << 2;
      int gr = row0 + r;
      float4 v = make_float4(0.f, 0.f, 0.f, 0.f);
      if (gr < M) v = *(const float4*)(A + (size_t)gr * D + k0 + kq);
      As[kq + 0][r] = v.x;
      As[kq + 1][r] = v.y;
      As[kq + 2][r] = v.z;
      As[kq + 3][r] = v.w;
    }
    {  // stage W tile: Ws[k][c]  (16*16 float4 = 256 threads, one each)
      int k = threadIdx.x >> 4;
      int c4 = (threadIdx.x & 15) << 2;
      *(float4*)(&Ws[k][c4]) = *(const float4*)(W + (size_t)(k0 + k) * BN + c4);
    }
    __syncthreads();
#pragma unroll
    for (int k = 0; k < BK; ++k) {
      float a[4];
#pragma unroll
      for (int r = 0; r < 4; ++r) a[r] = As[k][ty * 4 + r];
      float w[TCOL];
#pragma unroll
      for (int c = 0; c < TCOL; ++c) w[c] = Ws[k][tx * TCOL + c];
#pragma unroll
      for (int r = 0; r < 4; ++r)
#pragma unroll
        for (int c = 0; c < TCOL; ++c) acc[r][c] += a[r] * w[c];
    }
    __syncthreads();
  }
#pragma unroll
  for (int r = 0; r < 4; ++r) {
    int gr = row0 + ty * 4 + r;
    if (gr < M) {
      ushort4 pk;
      pk.x = f2bf(acc[r][0]);
      pk.y = f2bf(acc[r][1]);
      pk.z = f2bf(acc[r][2]);
      pk.w = f2bf(acc[r][3]);
      *(ushort4*)(C + (size_t)gr * BN + tx * TCOL) = pk;  // 8B coalesced store
    }
  }
}

// ============ 64-wide aggregation over bf16 table ============
// Validated uniform-trip structure + 4-deep manual unroll: 4 independent row
// loads in flight per iteration (m is wave-uniform -> no divergence; the R3
// failure was the divergent-trip group variant, not revisited).
// FIN: Y += 1.7*s(v)*c + 1.7*b2, s(v) = 1.7 + 0.9*deg1 + 0.8*deg2.

template <int FIN, int OUT_BF16>
__global__ __launch_bounds__(256) void agg64_kernel(const unsigned short* __restrict__ X,
                                                    const int* __restrict__ off,
                                                    const int* __restrict__ adj,
                                                    const float* __restrict__ cvec,
                                                    const float* __restrict__ b2,
                                                    void* __restrict__ Yv) {
  int wid = (blockIdx.x * blockDim.x + threadIdx.x) >> 6;  // node
  if (wid >= N_NODES) return;
  int lane = threadIdx.x & 63;

  float self = bf2f(X[(size_t)wid * 64 + lane]);

  int s1 = off[wid], e1 = off[wid + 1];
  int s2 = off[N_NODES + wid], e2 = off[N_NODES + wid + 1];

  float acc[2];
#pragma unroll
  for (int g = 0; g < 2; ++g) {
    int s = g ? s2 : s1, e = g ? e2 : e1;
    float a0 = 0.f, a1 = 0.f, a2 = 0.f, a3 = 0.f;
    for (int base = s; base < e; base += 64) {
      int m = e - base;
      if (m > 64) m = 64;
      int idx = (lane < m) ? adj[base + lane] : 0;  // coalesced index batch
      int i = 0;
      for (; i + 4 <= m; i += 4) {                  // uniform trip, 4 loads in flight
        int n0 = __shfl(idx, i + 0);
        int n1 = __shfl(idx, i + 1);
        int n2 = __shfl(idx, i + 2);
        int n3 = __shfl(idx, i + 3);
        float f0 = bf2f(X[(size_t)n0 * 64 + lane]);
        float f1 = bf2f(X[(size_t)n1 * 64 + lane]);
        float f2 = bf2f(X[(size_t)n2 * 64 + lane]);
        float f3 = bf2f(X[(size_t)n3 * 64 + lane]);
        a0 += f0; a1 += f1; a2 += f2; a3 += f3;
      }
      for (; i < m; ++i) {                          // uniform tail
        int n0 = __shfl(idx, i);
        a0 += bf2f(X[(size_t)n0 * 64 + lane]);
      }
    }
    acc[g] = (a0 + a1) + (a2 + a3);
  }
  float y = 1.7f * self + 0.9f * acc[0] + 0.8f * acc[1];
  if (FIN) {
    float sv = 1.7f * (1.7f + 0.9f * (float)(e1 - s1) + 0.8f * (float)(e2 - s2));
    y += sv * cvec[lane] + 1.7f * b2[lane];
  }
  if (OUT_BF16) {
    ((unsigned short*)Yv)[(size_t)wid * 64 + lane] = f2bf(y);
  } else {
    ((float*)Yv)[(size_t)wid * 64 + lane] = y;
  }
}

// ============ launch ============
// Math: gates == 1 (softmax over size-1 axis), so with L(X) = 1.7X + 0.9*A1X + 0.8*A2X:
//   out = L(L(F @ W12)) + 1.7*s(v)*(b1@W2) + 1.7*b2    (pushdown is exact; validated R5)
// Gather tables H,T in bf16; CSR built via 2-level binning (write locality).

extern "C" void kernel_launch(void* const* d_in, const int* in_sizes, int n_in,
                              void* d_out, int out_size, void* d_ws, size_t ws_size,
                              hipStream_t stream) {
  const float* F  = (const float*)d_in[0];
  const int* src1 = (const int*)d_in[1];
  const int* dst1 = (const int*)d_in[2];
  const int* src2 = (const int*)d_in[3];
  const int* dst2 = (const int*)d_in[4];
  const float* W1 = (const float*)d_in[5];
  const float* b1 = (const float*)d_in[6];
  const float* W2 = (const float*)d_in[7];
  const float* b2 = (const float*)d_in[8];
  // d_in[9..16] (gate weights) are dead: softmax over a size-1 axis == 1.
  float* out = (float*)d_out;

  char* ws = (char*)d_ws;
  auto aln = [](size_t x) { return (x + 255) & ~(size_t)255; };
  size_t o = 0;
  int* cnt_cur = (int*)(ws + o); o = aln(o + (size_t)2 * N_NODES * 4);
  int* off     = (int*)(ws + o); o = aln(o + ((size_t)2 * N_NODES + 1) * 4);
  int* bsum    = (int*)(ws + o); o = aln(o + 256 * 4);
  int* bincnt  = (int*)(ws + o); o = aln(o + (size_t)NBINS * BCNT_STRIDE * 4);
  int2* binbuf = (int2*)(ws + o); o = aln(o + (size_t)NBINS * BIN_CAP * 8);
  int* adj     = (int*)(ws + o); o = aln(o + (size_t)2 * N_EDGES * 4);
  float* W12   = (float*)(ws + o); o = aln(o + (size_t)D * NCLS * 4);
  float* cvec  = (float*)(ws + o); o = aln(o + NCLS * 4);
  unsigned short* H = (unsigned short*)(ws + o); o = aln(o + (size_t)N_NODES * NCLS * 2);
  unsigned short* T = (unsigned short*)(ws + o); o = aln(o + (size_t)N_NODES * NCLS * 2);
  (void)ws_size;  // ~38 MB used

  // CSR build (binned)
  hipMemsetAsync(bincnt, 0, (size_t)NBINS * BCNT_STRIDE * 4, stream);
  bin_scatter<<<(2 * N_EDGES + 255) / 256, 256, 0, stream>>>(src1, dst1, src2, dst2, bincnt, binbuf);
  bin_hist<<<NBINS, 256, 0, stream>>>(bincnt, binbuf, cnt_cur);
  const int NB = (2 * N_NODES + SCAN_B - 1) / SCAN_B;  // 98
  scan_local<<<NB, SCAN_B, 0, stream>>>(cnt_cur, off, bsum, 2 * N_NODES);
  scan_tops<<<1, 128, 0, stream>>>(bsum, NB, off, 2 * N_NODES);
  scan_add<<<NB, SCAN_B, 0, stream>>>(off, cnt_cur, bsum, 2 * N_NODES);
  bin_fill<<<NBINS, 256, 0, stream>>>(bincnt, binbuf, cnt_cur, adj);

  // weights: W12 = W1@W2, c = b1@W2
  w12_kernel<<<32, 256, 0, stream>>>(W1, W2, b1, W12, cvec);
  // H = bf16(F @ W12)
  gemm64_kernel<<<(N_NODES + 63) / 64, 256, 0, stream>>>(F, W12, H, N_NODES);
  // T = bf16(L(H))
  agg64_kernel<0, 1><<<N_NODES / 4, 256, 0, stream>>>(H, off, adj, cvec, b2, T);
  // out = L(T) + 1.7*s(v)*c + 1.7*b2   (f32)
  agg64_kernel<1, 0><<<N_NODES / 4, 256, 0, stream>>>(T, off, adj, cvec, b2, out);
}

// Round 8
// 261.944 us; speedup vs baseline: 1.8189x; 1.1786x over previous
//
#include <hip/hip_runtime.h>

#define N_NODES 50000
#define N_EDGES 600000
#define D 128   // D_IN == HID
#define NCLS 64

// Binned CSR build: rows 0..2N-1 (graph1 then graph2), 512 rows/bin
#define BIN_SHIFT 9
#define BIN_ROWS 512
#define NBINS 196        // ceil(100000/512)
#define BIN_CAP 8192     // mean 6122, sd 78 -> +26 sigma
#define CHUNK 4096       // edges per multisplit block
#define EPT (CHUNK / 256)

// bf16 helpers (tables only; all arithmetic stays f32)
__device__ inline unsigned short f2bf(float f) {
  unsigned int u = __float_as_uint(f);
  unsigned int r = (u + 0x7FFF + ((u >> 16) & 1)) >> 16;  // RNE
  return (unsigned short)r;
}
__device__ inline float bf2f(unsigned short b) {
  return __uint_as_float(((unsigned int)b) << 16);
}

// ============ pass 1: block-local multisplit scatter ============
// Stage CHUNK edges in LDS grouped by bin, reserve per-bin global space with
// one atomic per (block,bin), flush contiguous runs (~21 entries) coalesced.

__global__ __launch_bounds__(256) void ms_scatter(const int* __restrict__ src1,
                                                  const int* __restrict__ dst1,
                                                  const int* __restrict__ src2,
                                                  const int* __restrict__ dst2,
                                                  int* __restrict__ bincnt,
                                                  int2* __restrict__ binbuf) {
  __shared__ int bcnt[NBINS];    // count, then placement cursor
  __shared__ int boff[NBINS];    // local exclusive prefix
  __shared__ int gbase[NBINS];   // stashed count, then global base
  __shared__ int stmp[256];
  __shared__ int2 stage[CHUNK];

  int base = blockIdx.x * CHUNK;
  int nloc = min(CHUNK, 2 * N_EDGES - base);

  for (int t = threadIdx.x; t < NBINS; t += 256) bcnt[t] = 0;
  __syncthreads();

  int rows[EPT], srcs[EPT], bins[EPT];
#pragma unroll
  for (int k = 0; k < EPT; ++k) {
    int t = threadIdx.x + k * 256;  // coalesced
    rows[k] = -1;
    if (t < nloc) {
      int i = base + t;
      int row, sv;
      if (i < N_EDGES) { row = dst1[i]; sv = src1[i]; }
      else { int e = i - N_EDGES; row = N_NODES + dst2[e]; sv = src2[e]; }
      rows[k] = row; srcs[k] = sv;
      bins[k] = row >> BIN_SHIFT;
      atomicAdd(&bcnt[bins[k]], 1);
    }
  }
  __syncthreads();
  {  // exclusive scan bcnt -> boff (NBINS <= 256)
    int tid = threadIdx.x;
    int v = (tid < NBINS) ? bcnt[tid] : 0;
    stmp[tid] = v;
    __syncthreads();
    int x = v;
    for (int o = 1; o < 256; o <<= 1) {
      int y = (tid >= o) ? stmp[tid - o] : 0;
      __syncthreads();
      x += y;
      stmp[tid] = x;
      __syncthreads();
    }
    if (tid < NBINS) boff[tid] = x - v;
  }
  __syncthreads();
  for (int t = threadIdx.x; t < NBINS; t += 256) {  // stash count; init cursor
    gbase[t] = bcnt[t];
    bcnt[t] = boff[t];
  }
  __syncthreads();
#pragma unroll
  for (int k = 0; k < EPT; ++k) {  // rank + place into bin-grouped LDS
    if (rows[k] >= 0) {
      int p = atomicAdd(&bcnt[bins[k]], 1);
      stage[p] = make_int2(rows[k], srcs[k]);
    }
  }
  __syncthreads();
  for (int t = threadIdx.x; t < NBINS; t += 256) {  // one global atomic per bin
    int c = gbase[t];
    if (c > 0) gbase[t] = atomicAdd(&bincnt[t], c);
  }
  __syncthreads();
  for (int j = threadIdx.x; j < nloc; j += 256) {  // flush contiguous runs
    int2 e = stage[j];
    int b = e.x >> BIN_SHIFT;
    int gp = gbase[b] + (j - boff[b]);
    if (gp < BIN_CAP) binbuf[(size_t)b * BIN_CAP + gp] = e;
  }
}

// ============ per-bin histogram via LDS ============

__global__ __launch_bounds__(256) void bin_hist(const int* __restrict__ bincnt,
                                                const int2* __restrict__ binbuf,
                                                int* __restrict__ cnt) {
  __shared__ int lc[BIN_ROWS];
  int b = blockIdx.x;
  for (int t = threadIdx.x; t < BIN_ROWS; t += 256) lc[t] = 0;
  __syncthreads();
  int n = min(bincnt[b], BIN_CAP);
  for (int t = threadIdx.x; t < n; t += 256) {
    int row = binbuf[(size_t)b * BIN_CAP + t].x;
    atomicAdd(&lc[row & (BIN_ROWS - 1)], 1);
  }
  __syncthreads();
  for (int t = threadIdx.x; t < BIN_ROWS; t += 256) {
    int row = (b << BIN_SHIFT) + t;
    if (row < 2 * N_NODES) cnt[row] = lc[t];
  }
}

// ============ scans (unchanged, HW-validated) ============

#define SCAN_B 1024
__global__ void scan_local(const int* __restrict__ cnt, int* __restrict__ off,
                           int* __restrict__ bsum, int n) {
  __shared__ int sh[SCAN_B];
  int tid = threadIdx.x;
  int gid = blockIdx.x * SCAN_B + tid;
  int v = (gid < n) ? cnt[gid] : 0;
  sh[tid] = v;
  __syncthreads();
  int x = v;
  for (int o = 1; o < SCAN_B; o <<= 1) {
    int y = (tid >= o) ? sh[tid - o] : 0;
    __syncthreads();
    x += y;
    sh[tid] = x;
    __syncthreads();
  }
  if (gid < n) off[gid] = x - v;            // exclusive (pre-carry)
  if (tid == SCAN_B - 1) bsum[blockIdx.x] = x;
}

__global__ void scan_tops(int* __restrict__ bsum, int nb, int* __restrict__ off, int last) {
  __shared__ int sh[128];
  int tid = threadIdx.x;
  int v = (tid < nb) ? bsum[tid] : 0;
  sh[tid] = v;
  __syncthreads();
  int x = v;
  for (int o = 1; o < 128; o <<= 1) {
    int y = (tid >= o) ? sh[tid - o] : 0;
    __syncthreads();
    x += y;
    sh[tid] = x;
    __syncthreads();
  }
  if (tid < nb) bsum[tid] = x - v;   // exclusive block prefix
  if (tid == 127) off[last] = x;     // total == 2E
}

__global__ void scan_add(int* __restrict__ off, int* __restrict__ cur,
                         const int* __restrict__ bsum, int n) {
  int gid = blockIdx.x * SCAN_B + threadIdx.x;
  if (gid < n) {
    int o = off[gid] + bsum[blockIdx.x];
    off[gid] = o;
    cur[gid] = o;
  }
}

// ============ pass 2: bin-local fill (adj writes land in ~25KB contiguous range) ============

__global__ __launch_bounds__(256) void bin_fill(const int* __restrict__ bincnt,
                                                const int2* __restrict__ binbuf,
                                                int* __restrict__ cur, int* __restrict__ adj) {
  int b = blockIdx.x;
  int n = min(bincnt[b], BIN_CAP);
  for (int t = threadIdx.x; t < n; t += 256) {
    int2 e = binbuf[(size_t)b * BIN_CAP + t];
    int p = atomicAdd(&cur[e.x], 1);
    adj[p] = e.y;
  }
}

// ============ micro-GEMM: W12 = W1@W2 (128x64), c = b1@W2 (64) ============

__global__ void w12_kernel(const float* __restrict__ W1, const float* __restrict__ W2,
                           const float* __restrict__ b1,
                           float* __restrict__ W12, float* __restrict__ c) {
  int o = blockIdx.x * blockDim.x + threadIdx.x;  // 0..8191
  int i = o >> 6, j = o & 63;
  float s = 0.f;
  for (int k = 0; k < D; ++k) s += W1[i * D + k] * W2[k * NCLS + j];
  W12[i * NCLS + j] = s;
  if (o < NCLS) {
    float t = 0.f;
    for (int k = 0; k < D; ++k) t += b1[k] * W2[k * NCLS + o];
    c[o] = t;
  }
}

// ============ GEMM: H[M,64] = A[M,128] @ W[128,64], output stored as bf16 ============

__global__ __launch_bounds__(256) void gemm64_kernel(const float* __restrict__ A,
                                                     const float* __restrict__ W,
                                                     unsigned short* __restrict__ C, int M) {
  constexpr int BM = 64, BK = 16, BN = 64;
  constexpr int TCOL = BN / 16;  // 4
  __shared__ float As[BK][BM + 1];
  __shared__ float Ws[BK][BN];
  const int tx = threadIdx.x & 15;
  const int ty = threadIdx.x >> 4;
  const int row0 = blockIdx.x * BM;
  float acc[4][TCOL];
#pragma unroll
  for (int r = 0; r < 4; ++r)
#pragma unroll
    for (int c = 0; c < TCOL; ++c) acc[r][c] = 0.f;

  for (int k0 = 0; k0 < D; k0 += BK) {
    {  // stage A tile transposed: As[k][row]
      int t = threadIdx.x;
      int r = t >> 2;
      int kq = (t & 3) << 2;
      int gr = row0 + r;
      float4 v = make_float4(0.f, 0.f, 0.f, 0.f);
      if (gr < M) v = *(const float4*)(A + (size_t)gr * D + k0 + kq);
      As[kq + 0][r] = v.x;
      As[kq + 1][r] = v.y;
      As[kq + 2][r] = v.z;
      As[kq + 3][r] = v.w;
    }
    {  // stage W tile: Ws[k][c]  (16*16 float4 = 256 threads, one each)
      int k = threadIdx.x >> 4;
      int c4 = (threadIdx.x & 15) << 2;
      *(float4*)(&Ws[k][c4]) = *(const float4*)(W + (size_t)(k0 + k) * BN + c4);
    }
    __syncthreads();
#pragma unroll
    for (int k = 0; k < BK; ++k) {
      float a[4];
#pragma unroll
      for (int r = 0; r < 4; ++r) a[r] = As[k][ty * 4 + r];
      float w[TCOL];
#pragma unroll
      for (int c = 0; c < TCOL; ++c) w[c] = Ws[k][tx * TCOL + c];
#pragma unroll
      for (int r = 0; r < 4; ++r)
#pragma unroll
        for (int c = 0; c < TCOL; ++c) acc[r][c] += a[r] * w[c];
    }
    __syncthreads();
  }
#pragma unroll
  for (int r = 0; r < 4; ++r) {
    int gr = row0 + ty * 4 + r;
    if (gr < M) {
      ushort4 pk;
      pk.x = f2bf(acc[r][0]);
      pk.y = f2bf(acc[r][1]);
      pk.z = f2bf(acc[r][2]);
      pk.w = f2bf(acc[r][3]);
      *(ushort4*)(C + (size_t)gr * BN + tx * TCOL) = pk;  // 8B coalesced store
    }
  }
}

// ============ 64-wide aggregation over bf16 table (validated + 4-deep unroll) ============
// FIN: Y += 1.7*s(v)*c + 1.7*b2, s(v) = 1.7 + 0.9*deg1 + 0.8*deg2.

template <int FIN, int OUT_BF16>
__global__ __launch_bounds__(256) void agg64_kernel(const unsigned short* __restrict__ X,
                                                    const int* __restrict__ off,
                                                    const int* __restrict__ adj,
                                                    const float* __restrict__ cvec,
                                                    const float* __restrict__ b2,
                                                    void* __restrict__ Yv) {
  int wid = (blockIdx.x * blockDim.x + threadIdx.x) >> 6;  // node
  if (wid >= N_NODES) return;
  int lane = threadIdx.x & 63;

  float self = bf2f(X[(size_t)wid * 64 + lane]);

  int s1 = off[wid], e1 = off[wid + 1];
  int s2 = off[N_NODES + wid], e2 = off[N_NODES + wid + 1];

  float acc[2];
#pragma unroll
  for (int g = 0; g < 2; ++g) {
    int s = g ? s2 : s1, e = g ? e2 : e1;
    float a0 = 0.f, a1 = 0.f, a2 = 0.f, a3 = 0.f;
    for (int base = s; base < e; base += 64) {
      int m = e - base;
      if (m > 64) m = 64;
      int idx = (lane < m) ? adj[base + lane] : 0;  // coalesced index batch
      int i = 0;
      for (; i + 4 <= m; i += 4) {                  // uniform trip, 4 loads in flight
        int n0 = __shfl(idx, i + 0);
        int n1 = __shfl(idx, i + 1);
        int n2 = __shfl(idx, i + 2);
        int n3 = __shfl(idx, i + 3);
        float f0 = bf2f(X[(size_t)n0 * 64 + lane]);
        float f1 = bf2f(X[(size_t)n1 * 64 + lane]);
        float f2 = bf2f(X[(size_t)n2 * 64 + lane]);
        float f3 = bf2f(X[(size_t)n3 * 64 + lane]);
        a0 += f0; a1 += f1; a2 += f2; a3 += f3;
      }
      for (; i < m; ++i) {                          // uniform tail
        int n0 = __shfl(idx, i);
        a0 += bf2f(X[(size_t)n0 * 64 + lane]);
      }
    }
    acc[g] = (a0 + a1) + (a2 + a3);
  }
  float y = 1.7f * self + 0.9f * acc[0] + 0.8f * acc[1];
  if (FIN) {
    float sv = 1.7f * (1.7f + 0.9f * (float)(e1 - s1) + 0.8f * (float)(e2 - s2));
    y += sv * cvec[lane] + 1.7f * b2[lane];
  }
  if (OUT_BF16) {
    ((unsigned short*)Yv)[(size_t)wid * 64 + lane] = f2bf(y);
  } else {
    ((float*)Yv)[(size_t)wid * 64 + lane] = y;
  }
}

// ============ launch ============
// Math: gates == 1 (softmax over size-1 axis), so with L(X) = 1.7X + 0.9*A1X + 0.8*A2X:
//   out = L(L(F @ W12)) + 1.7*s(v)*(b1@W2) + 1.7*b2    (pushdown exact; validated R5)
// Gather tables H,T in bf16; CSR via multisplit binning (write locality).

extern "C" void kernel_launch(void* const* d_in, const int* in_sizes, int n_in,
                              void* d_out, int out_size, void* d_ws, size_t ws_size,
                              hipStream_t stream) {
  const float* F  = (const float*)d_in[0];
  const int* src1 = (const int*)d_in[1];
  const int* dst1 = (const int*)d_in[2];
  const int* src2 = (const int*)d_in[3];
  const int* dst2 = (const int*)d_in[4];
  const float* W1 = (const float*)d_in[5];
  const float* b1 = (const float*)d_in[6];
  const float* W2 = (const float*)d_in[7];
  const float* b2 = (const float*)d_in[8];
  // d_in[9..16] (gate weights) are dead: softmax over a size-1 axis == 1.
  float* out = (float*)d_out;

  char* ws = (char*)d_ws;
  auto aln = [](size_t x) { return (x + 255) & ~(size_t)255; };
  size_t o = 0;
  int* cnt_cur = (int*)(ws + o); o = aln(o + (size_t)2 * N_NODES * 4);
  int* off     = (int*)(ws + o); o = aln(o + ((size_t)2 * N_NODES + 1) * 4);
  int* bsum    = (int*)(ws + o); o = aln(o + 256 * 4);
  int* bincnt  = (int*)(ws + o); o = aln(o + (size_t)NBINS * 4);
  int2* binbuf = (int2*)(ws + o); o = aln(o + (size_t)NBINS * BIN_CAP * 8);
  int* adj     = (int*)(ws + o); o = aln(o + (size_t)2 * N_EDGES * 4);
  float* W12   = (float*)(ws + o); o = aln(o + (size_t)D * NCLS * 4);
  float* cvec  = (float*)(ws + o); o = aln(o + NCLS * 4);
  unsigned short* H = (unsigned short*)(ws + o); o = aln(o + (size_t)N_NODES * NCLS * 2);
  unsigned short* T = (unsigned short*)(ws + o); o = aln(o + (size_t)N_NODES * NCLS * 2);
  (void)ws_size;  // ~38 MB used

  // CSR build (multisplit binning)
  hipMemsetAsync(bincnt, 0, (size_t)NBINS * 4, stream);
  ms_scatter<<<(2 * N_EDGES + CHUNK - 1) / CHUNK, 256, 0, stream>>>(src1, dst1, src2, dst2,
                                                                    bincnt, binbuf);
  bin_hist<<<NBINS, 256, 0, stream>>>(bincnt, binbuf, cnt_cur);
  const int NB = (2 * N_NODES + SCAN_B - 1) / SCAN_B;  // 98
  scan_local<<<NB, SCAN_B, 0, stream>>>(cnt_cur, off, bsum, 2 * N_NODES);
  scan_tops<<<1, 128, 0, stream>>>(bsum, NB, off, 2 * N_NODES);
  scan_add<<<NB, SCAN_B, 0, stream>>>(off, cnt_cur, bsum, 2 * N_NODES);
  bin_fill<<<NBINS, 256, 0, stream>>>(bincnt, binbuf, cnt_cur, adj);

  // weights: W12 = W1@W2, c = b1@W2
  w12_kernel<<<32, 256, 0, stream>>>(W1, W2, b1, W12, cvec);
  // H = bf16(F @ W12)
  gemm64_kernel<<<(N_NODES + 63) / 64, 256, 0, stream>>>(F, W12, H, N_NODES);
  // T = bf16(L(H))
  agg64_kernel<0, 1><<<N_NODES / 4, 256, 0, stream>>>(H, off, adj, cvec, b2, T);
  // out = L(T) + 1.7*s(v)*c + 1.7*b2   (f32)
  agg64_kernel<1, 0><<<N_NODES / 4, 256, 0, stream>>>(T, off, adj, cvec, b2, out);
}

// Round 9
// 232.658 us; speedup vs baseline: 2.0478x; 1.1259x over previous
//
#include <hip/hip_runtime.h>

#define N_NODES 50000
#define N_EDGES 600000
#define D 128   // D_IN == HID
#define NCLS 64

// Binned CSR build: rows 0..2N-1 (graph1 then graph2), 512 rows/bin
#define BIN_SHIFT 9
#define BIN_ROWS 512
#define NBINS 196        // ceil(100000/512)
#define BIN_CAP 8192     // mean 6122, sd 78 -> +26 sigma
#define CHUNK 4096       // edges per multisplit block
#define EPT (CHUNK / 256)

// bf16 helpers (tables only; all arithmetic stays f32)
__device__ inline unsigned short f2bf(float f) {
  unsigned int u = __float_as_uint(f);
  unsigned int r = (u + 0x7FFF + ((u >> 16) & 1)) >> 16;  // RNE
  return (unsigned short)r;
}
__device__ inline float bf2f(unsigned short b) {
  return __uint_as_float(((unsigned int)b) << 16);
}

// ============ pass 1: block-local multisplit scatter (HW-validated R8) ============

__global__ __launch_bounds__(256) void ms_scatter(const int* __restrict__ src1,
                                                  const int* __restrict__ dst1,
                                                  const int* __restrict__ src2,
                                                  const int* __restrict__ dst2,
                                                  int* __restrict__ bincnt,
                                                  int2* __restrict__ binbuf) {
  __shared__ int bcnt[NBINS];    // count, then placement cursor
  __shared__ int boff[NBINS];    // local exclusive prefix
  __shared__ int gbase[NBINS];   // stashed count, then global base
  __shared__ int stmp[256];
  __shared__ int2 stage[CHUNK];

  int base = blockIdx.x * CHUNK;
  int nloc = min(CHUNK, 2 * N_EDGES - base);

  for (int t = threadIdx.x; t < NBINS; t += 256) bcnt[t] = 0;
  __syncthreads();

  int rows[EPT], srcs[EPT], bins[EPT];
#pragma unroll
  for (int k = 0; k < EPT; ++k) {
    int t = threadIdx.x + k * 256;  // coalesced
    rows[k] = -1;
    if (t < nloc) {
      int i = base + t;
      int row, sv;
      if (i < N_EDGES) { row = dst1[i]; sv = src1[i]; }
      else { int e = i - N_EDGES; row = N_NODES + dst2[e]; sv = src2[e]; }
      rows[k] = row; srcs[k] = sv;
      bins[k] = row >> BIN_SHIFT;
      atomicAdd(&bcnt[bins[k]], 1);
    }
  }
  __syncthreads();
  {  // exclusive scan bcnt -> boff (NBINS <= 256)
    int tid = threadIdx.x;
    int v = (tid < NBINS) ? bcnt[tid] : 0;
    stmp[tid] = v;
    __syncthreads();
    int x = v;
    for (int o = 1; o < 256; o <<= 1) {
      int y = (tid >= o) ? stmp[tid - o] : 0;
      __syncthreads();
      x += y;
      stmp[tid] = x;
      __syncthreads();
    }
    if (tid < NBINS) boff[tid] = x - v;
  }
  __syncthreads();
  for (int t = threadIdx.x; t < NBINS; t += 256) {  // stash count; init cursor
    gbase[t] = bcnt[t];
    bcnt[t] = boff[t];
  }
  __syncthreads();
#pragma unroll
  for (int k = 0; k < EPT; ++k) {  // rank + place into bin-grouped LDS
    if (rows[k] >= 0) {
      int p = atomicAdd(&bcnt[bins[k]], 1);
      stage[p] = make_int2(rows[k], srcs[k]);
    }
  }
  __syncthreads();
  for (int t = threadIdx.x; t < NBINS; t += 256) {  // one global atomic per bin
    int c = gbase[t];
    if (c > 0) gbase[t] = atomicAdd(&bincnt[t], c);
  }
  __syncthreads();
  for (int j = threadIdx.x; j < nloc; j += 256) {  // flush contiguous runs
    int2 e = stage[j];
    int b = e.x >> BIN_SHIFT;
    int gp = gbase[b] + (j - boff[b]);
    if (gp < BIN_CAP) binbuf[(size_t)b * BIN_CAP + gp] = e;
  }
}

// ============ tiny scan: binbase = exclusive_scan(bincnt), off[2N] = total ============
// (bincnt after ms_scatter already holds exact per-bin totals)

__global__ void scan_bins(const int* __restrict__ bincnt, int* __restrict__ binbase,
                          int* __restrict__ off) {
  __shared__ int sh[256];
  int tid = threadIdx.x;
  int v = (tid < NBINS) ? bincnt[tid] : 0;
  sh[tid] = v;
  __syncthreads();
  int x = v;
  for (int o = 1; o < 256; o <<= 1) {
    int y = (tid >= o) ? sh[tid - o] : 0;
    __syncthreads();
    x += y;
    sh[tid] = x;
    __syncthreads();
  }
  if (tid < NBINS) binbase[tid] = x - v;
  if (tid == 255) off[2 * N_NODES] = x;   // == 2E
}

// ============ pass 2: per-bin hist + scan + off-write + fill via LDS cursors ============
// One block per bin (512 threads = 512 rows). Replaces bin_hist + 3 global
// scans + global-atomic bin_fill: off[row] = binbase[b] + local_prefix, adj
// placed through LDS cursors -> all adj writes land in the bin's ~24KB window.

__global__ __launch_bounds__(512) void bin_build(const int* __restrict__ bincnt,
                                                 const int* __restrict__ binbase,
                                                 const int2* __restrict__ binbuf,
                                                 int* __restrict__ off, int* __restrict__ adj) {
  __shared__ int sh[BIN_ROWS];   // counts -> inclusive scan -> cursors
  __shared__ int lp[BIN_ROWS];   // local exclusive prefix
  int b = blockIdx.x;
  int tid = threadIdx.x;
  int n = min(bincnt[b], BIN_CAP);
  int base = binbase[b];

  sh[tid] = 0;
  __syncthreads();
  for (int t = tid; t < n; t += 512) {
    int row = binbuf[(size_t)b * BIN_CAP + t].x;
    atomicAdd(&sh[row & (BIN_ROWS - 1)], 1);
  }
  __syncthreads();
  int v = sh[tid];
  int x = v;
  for (int o = 1; o < BIN_ROWS; o <<= 1) {   // validated Hillis-Steele pattern
    int y = (tid >= o) ? sh[tid - o] : 0;
    __syncthreads();
    x += y;
    sh[tid] = x;
    __syncthreads();
  }
  lp[tid] = x - v;                            // exclusive local prefix
  int row = (b << BIN_SHIFT) + tid;
  if (row < 2 * N_NODES) off[row] = base + lp[tid];
  __syncthreads();
  sh[tid] = lp[tid];                          // cursors
  __syncthreads();
  for (int t = tid; t < n; t += 512) {
    int2 e = binbuf[(size_t)b * BIN_CAP + t];
    int p = atomicAdd(&sh[e.x & (BIN_ROWS - 1)], 1);
    adj[base + p] = e.y;                      // bin-local contiguous window
  }
}

// ============ micro-GEMM: W12 = W1@W2 (128x64), c = b1@W2 (64) ============

__global__ void w12_kernel(const float* __restrict__ W1, const float* __restrict__ W2,
                           const float* __restrict__ b1,
                           float* __restrict__ W12, float* __restrict__ c) {
  int o = blockIdx.x * blockDim.x + threadIdx.x;  // 0..8191
  int i = o >> 6, j = o & 63;
  float s = 0.f;
  for (int k = 0; k < D; ++k) s += W1[i * D + k] * W2[k * NCLS + j];
  W12[i * NCLS + j] = s;
  if (o < NCLS) {
    float t = 0.f;
    for (int k = 0; k < D; ++k) t += b1[k] * W2[k * NCLS + o];
    c[o] = t;
  }
}

// ============ GEMM: H[M,64] = A[M,128] @ W[128,64], output stored as bf16 ============

__global__ __launch_bounds__(256) void gemm64_kernel(const float* __restrict__ A,
                                                     const float* __restrict__ W,
                                                     unsigned short* __restrict__ C, int M) {
  constexpr int BM = 64, BK = 16, BN = 64;
  constexpr int TCOL = BN / 16;  // 4
  __shared__ float As[BK][BM + 1];
  __shared__ float Ws[BK][BN];
  const int tx = threadIdx.x & 15;
  const int ty = threadIdx.x >> 4;
  const int row0 = blockIdx.x * BM;
  float acc[4][TCOL];
#pragma unroll
  for (int r = 0; r < 4; ++r)
#pragma unroll
    for (int c = 0; c < TCOL; ++c) acc[r][c] = 0.f;

  for (int k0 = 0; k0 < D; k0 += BK) {
    {  // stage A tile transposed: As[k][row]
      int t = threadIdx.x;
      int r = t >> 2;
      int kq = (t & 3) << 2;
      int gr = row0 + r;
      float4 v = make_float4(0.f, 0.f, 0.f, 0.f);
      if (gr < M) v = *(const float4*)(A + (size_t)gr * D + k0 + kq);
      As[kq + 0][r] = v.x;
      As[kq + 1][r] = v.y;
      As[kq + 2][r] = v.z;
      As[kq + 3][r] = v.w;
    }
    {  // stage W tile: Ws[k][c]  (16*16 float4 = 256 threads, one each)
      int k = threadIdx.x >> 4;
      int c4 = (threadIdx.x & 15) << 2;
      *(float4*)(&Ws[k][c4]) = *(const float4*)(W + (size_t)(k0 + k) * BN + c4);
    }
    __syncthreads();
#pragma unroll
    for (int k = 0; k < BK; ++k) {
      float a[4];
#pragma unroll
      for (int r = 0; r < 4; ++r) a[r] = As[k][ty * 4 + r];
      float w[TCOL];
#pragma unroll
      for (int c = 0; c < TCOL; ++c) w[c] = Ws[k][tx * TCOL + c];
#pragma unroll
      for (int r = 0; r < 4; ++r)
#pragma unroll
        for (int c = 0; c < TCOL; ++c) acc[r][c] += a[r] * w[c];
    }
    __syncthreads();
  }
#pragma unroll
  for (int r = 0; r < 4; ++r) {
    int gr = row0 + ty * 4 + r;
    if (gr < M) {
      ushort4 pk;
      pk.x = f2bf(acc[r][0]);
      pk.y = f2bf(acc[r][1]);
      pk.z = f2bf(acc[r][2]);
      pk.w = f2bf(acc[r][3]);
      *(ushort4*)(C + (size_t)gr * BN + tx * TCOL) = pk;  // 8B coalesced store
    }
  }
}

// ============ 64-wide aggregation over bf16 table (validated + 4-deep unroll) ============
// FIN: Y += 1.7*s(v)*c + 1.7*b2, s(v) = 1.7 + 0.9*deg1 + 0.8*deg2.

template <int FIN, int OUT_BF16>
__global__ __launch_bounds__(256) void agg64_kernel(const unsigned short* __restrict__ X,
                                                    const int* __restrict__ off,
                                                    const int* __restrict__ adj,
                                                    const float* __restrict__ cvec,
                                                    const float* __restrict__ b2,
                                                    void* __restrict__ Yv) {
  int wid = (blockIdx.x * blockDim.x + threadIdx.x) >> 6;  // node
  if (wid >= N_NODES) return;
  int lane = threadIdx.x & 63;

  float self = bf2f(X[(size_t)wid * 64 + lane]);

  int s1 = off[wid], e1 = off[wid + 1];
  int s2 = off[N_NODES + wid], e2 = off[N_NODES + wid + 1];

  float acc[2];
#pragma unroll
  for (int g = 0; g < 2; ++g) {
    int s = g ? s2 : s1, e = g ? e2 : e1;
    float a0 = 0.f, a1 = 0.f, a2 = 0.f, a3 = 0.f;
    for (int base = s; base < e; base += 64) {
      int m = e - base;
      if (m > 64) m = 64;
      int idx = (lane < m) ? adj[base + lane] : 0;  // coalesced index batch
      int i = 0;
      for (; i + 4 <= m; i += 4) {                  // uniform trip, 4 loads in flight
        int n0 = __shfl(idx, i + 0);
        int n1 = __shfl(idx, i + 1);
        int n2 = __shfl(idx, i + 2);
        int n3 = __shfl(idx, i + 3);
        float f0 = bf2f(X[(size_t)n0 * 64 + lane]);
        float f1 = bf2f(X[(size_t)n1 * 64 + lane]);
        float f2 = bf2f(X[(size_t)n2 * 64 + lane]);
        float f3 = bf2f(X[(size_t)n3 * 64 + lane]);
        a0 += f0; a1 += f1; a2 += f2; a3 += f3;
      }
      for (; i < m; ++i) {                          // uniform tail
        int n0 = __shfl(idx, i);
        a0 += bf2f(X[(size_t)n0 * 64 + lane]);
      }
    }
    acc[g] = (a0 + a1) + (a2 + a3);
  }
  float y = 1.7f * self + 0.9f * acc[0] + 0.8f * acc[1];
  if (FIN) {
    float sv = 1.7f * (1.7f + 0.9f * (float)(e1 - s1) + 0.8f * (float)(e2 - s2));
    y += sv * cvec[lane] + 1.7f * b2[lane];
  }
  if (OUT_BF16) {
    ((unsigned short*)Yv)[(size_t)wid * 64 + lane] = f2bf(y);
  } else {
    ((float*)Yv)[(size_t)wid * 64 + lane] = y;
  }
}

// ============ launch ============
// Math: gates == 1 (softmax over size-1 axis), so with L(X) = 1.7X + 0.9*A1X + 0.8*A2X:
//   out = L(L(F @ W12)) + 1.7*s(v)*(b1@W2) + 1.7*b2    (pushdown exact; validated R5)
// Gather tables H,T in bf16; CSR via multisplit + hierarchical per-bin build.

extern "C" void kernel_launch(void* const* d_in, const int* in_sizes, int n_in,
                              void* d_out, int out_size, void* d_ws, size_t ws_size,
                              hipStream_t stream) {
  const float* F  = (const float*)d_in[0];
  const int* src1 = (const int*)d_in[1];
  const int* dst1 = (const int*)d_in[2];
  const int* src2 = (const int*)d_in[3];
  const int* dst2 = (const int*)d_in[4];
  const float* W1 = (const float*)d_in[5];
  const float* b1 = (const float*)d_in[6];
  const float* W2 = (const float*)d_in[7];
  const float* b2 = (const float*)d_in[8];
  // d_in[9..16] (gate weights) are dead: softmax over a size-1 axis == 1.
  float* out = (float*)d_out;

  char* ws = (char*)d_ws;
  auto aln = [](size_t x) { return (x + 255) & ~(size_t)255; };
  size_t o = 0;
  int* bincnt  = (int*)(ws + o); o = aln(o + (size_t)NBINS * 4);
  int* binbase = (int*)(ws + o); o = aln(o + (size_t)NBINS * 4);
  int* off     = (int*)(ws + o); o = aln(o + ((size_t)2 * N_NODES + 1) * 4);
  int2* binbuf = (int2*)(ws + o); o = aln(o + (size_t)NBINS * BIN_CAP * 8);
  int* adj     = (int*)(ws + o); o = aln(o + (size_t)2 * N_EDGES * 4);
  float* W12   = (float*)(ws + o); o = aln(o + (size_t)D * NCLS * 4);
  float* cvec  = (float*)(ws + o); o = aln(o + NCLS * 4);
  unsigned short* H = (unsigned short*)(ws + o); o = aln(o + (size_t)N_NODES * NCLS * 2);
  unsigned short* T = (unsigned short*)(ws + o); o = aln(o + (size_t)N_NODES * NCLS * 2);
  (void)ws_size;  // ~31 MB used

  // CSR build: scatter -> tiny bin scan -> per-bin build (off + adj)
  hipMemsetAsync(bincnt, 0, (size_t)NBINS * 4, stream);
  ms_scatter<<<(2 * N_EDGES + CHUNK - 1) / CHUNK, 256, 0, stream>>>(src1, dst1, src2, dst2,
                                                                    bincnt, binbuf);
  scan_bins<<<1, 256, 0, stream>>>(bincnt, binbase, off);
  bin_build<<<NBINS, 512, 0, stream>>>(bincnt, binbase, binbuf, off, adj);

  // weights: W12 = W1@W2, c = b1@W2
  w12_kernel<<<32, 256, 0, stream>>>(W1, W2, b1, W12, cvec);
  // H = bf16(F @ W12)
  gemm64_kernel<<<(N_NODES + 63) / 64, 256, 0, stream>>>(F, W12, H, N_NODES);
  // T = bf16(L(H))
  agg64_kernel<0, 1><<<N_NODES / 4, 256, 0, stream>>>(H, off, adj, cvec, b2, T);
  // out = L(T) + 1.7*s(v)*c + 1.7*b2   (f32)
  agg64_kernel<1, 0><<<N_NODES / 4, 256, 0, stream>>>(T, off, adj, cvec, b2, out);
}

// Round 10
// 211.191 us; speedup vs baseline: 2.2560x; 1.1016x over previous
//
#include <hip/hip_runtime.h>

#define N_NODES 50000
#define N_EDGES 600000
#define D 128   // D_IN == HID
#define NCLS 64

// Binned CSR build: rows 0..2N-1 (graph1 then graph2), 512 rows/bin
#define BIN_SHIFT 9
#define BIN_ROWS 512
#define NBINS 196        // ceil(100000/512)
#define BIN_CAP 8192     // mean 6122, sd 78 -> +26 sigma
#define CHUNK 4096       // edges per multisplit block
#define EPT (CHUNK / 256)
#define NCHUNKS 293      // ceil(2E/CHUNK)
#define W12_BLOCKS 17    // 17*256 = 4352 threads for 8256 outputs

// bf16 helpers (tables only; all arithmetic stays f32)
__device__ inline unsigned short f2bf(float f) {
  unsigned int u = __float_as_uint(f);
  unsigned int r = (u + 0x7FFF + ((u >> 16) & 1)) >> 16;  // RNE
  return (unsigned short)r;
}
__device__ inline float bf2f(unsigned short b) {
  return __uint_as_float(((unsigned int)b) << 16);
}

// ============ K1: multisplit scatter (blocks < NCHUNKS) + W12/cvec (blocks >= NCHUNKS) ============
// Scatter body is the HW-validated R8 ms_scatter, unchanged. w12 branch returns
// before any __syncthreads (block-uniform branch -> no barrier hazard).

__global__ __launch_bounds__(256) void scatter_w12(const int* __restrict__ src1,
                                                   const int* __restrict__ dst1,
                                                   const int* __restrict__ src2,
                                                   const int* __restrict__ dst2,
                                                   int* __restrict__ bincnt,
                                                   int2* __restrict__ binbuf,
                                                   const float* __restrict__ W1,
                                                   const float* __restrict__ W2,
                                                   const float* __restrict__ b1,
                                                   float* __restrict__ W12,
                                                   float* __restrict__ cvec) {
  __shared__ int bcnt[NBINS];
  __shared__ int boff[NBINS];
  __shared__ int gbase[NBINS];
  __shared__ int stmp[256];
  __shared__ int2 stage[CHUNK];

  if (blockIdx.x >= NCHUNKS) {  // ---- w12 part: W12 = W1@W2, cvec = b1@W2 ----
    int gid = (blockIdx.x - NCHUNKS) * 256 + threadIdx.x;
    for (int t = gid; t < D * NCLS + NCLS; t += W12_BLOCKS * 256) {
      if (t < D * NCLS) {
        int i = t >> 6, j = t & 63;
        float s = 0.f;
        for (int k = 0; k < D; ++k) s += W1[i * D + k] * W2[k * NCLS + j];
        W12[t] = s;
      } else {
        int j = t - D * NCLS;
        float s = 0.f;
        for (int k = 0; k < D; ++k) s += b1[k] * W2[k * NCLS + j];
        cvec[j] = s;
      }
    }
    return;
  }

  int base = blockIdx.x * CHUNK;
  int nloc = min(CHUNK, 2 * N_EDGES - base);

  for (int t = threadIdx.x; t < NBINS; t += 256) bcnt[t] = 0;
  __syncthreads();

  int rows[EPT], srcs[EPT], bins[EPT];
#pragma unroll
  for (int k = 0; k < EPT; ++k) {
    int t = threadIdx.x + k * 256;  // coalesced
    rows[k] = -1;
    if (t < nloc) {
      int i = base + t;
      int row, sv;
      if (i < N_EDGES) { row = dst1[i]; sv = src1[i]; }
      else { int e = i - N_EDGES; row = N_NODES + dst2[e]; sv = src2[e]; }
      rows[k] = row; srcs[k] = sv;
      bins[k] = row >> BIN_SHIFT;
      atomicAdd(&bcnt[bins[k]], 1);
    }
  }
  __syncthreads();
  {  // exclusive scan bcnt -> boff (NBINS <= 256)
    int tid = threadIdx.x;
    int v = (tid < NBINS) ? bcnt[tid] : 0;
    stmp[tid] = v;
    __syncthreads();
    int x = v;
    for (int o = 1; o < 256; o <<= 1) {
      int y = (tid >= o) ? stmp[tid - o] : 0;
      __syncthreads();
      x += y;
      stmp[tid] = x;
      __syncthreads();
    }
    if (tid < NBINS) boff[tid] = x - v;
  }
  __syncthreads();
  for (int t = threadIdx.x; t < NBINS; t += 256) {  // stash count; init cursor
    gbase[t] = bcnt[t];
    bcnt[t] = boff[t];
  }
  __syncthreads();
#pragma unroll
  for (int k = 0; k < EPT; ++k) {  // rank + place into bin-grouped LDS
    if (rows[k] >= 0) {
      int p = atomicAdd(&bcnt[bins[k]], 1);
      stage[p] = make_int2(rows[k], srcs[k]);
    }
  }
  __syncthreads();
  for (int t = threadIdx.x; t < NBINS; t += 256) {  // one global atomic per bin
    int c = gbase[t];
    if (c > 0) gbase[t] = atomicAdd(&bincnt[t], c);
  }
  __syncthreads();
  for (int j = threadIdx.x; j < nloc; j += 256) {  // flush contiguous runs
    int2 e = stage[j];
    int b = e.x >> BIN_SHIFT;
    int gp = gbase[b] + (j - boff[b]);
    if (gp < BIN_CAP) binbuf[(size_t)b * BIN_CAP + gp] = e;
  }
}

// ============ K2: bin_build (blocks < NBINS) + gemm64 (blocks >= NBINS), 512 threads ============
// bin_build body = validated R9 kernel + in-block bincnt prefix scan (replaces
// scan_bins dispatch). gemm body = validated gemm64 with work guarded tid<256;
// all __syncthreads unguarded at uniform nesting (k0 trip count is uniform).

__global__ __launch_bounds__(512) void build_gemm(const int* __restrict__ bincnt,
                                                  const int2* __restrict__ binbuf,
                                                  int* __restrict__ off, int* __restrict__ adj,
                                                  const float* __restrict__ A,
                                                  const float* __restrict__ W,
                                                  unsigned short* __restrict__ C) {
  __shared__ int sh[BIN_ROWS];
  __shared__ int lp[BIN_ROWS];
  __shared__ int stmp[256];
  __shared__ float As[16][65];
  __shared__ float Ws[16][64];

  int tid = threadIdx.x;

  if (blockIdx.x < NBINS) {  // ---- bin_build part ----
    int b = blockIdx.x;
    // prefix over bincnt (196 ints), threads 0..255 active, validated scan shape
    if (tid < 256) stmp[tid] = (tid < NBINS) ? bincnt[tid] : 0;
    __syncthreads();
    int x = (tid < 256) ? stmp[tid] : 0;
    for (int o = 1; o < 256; o <<= 1) {
      int y = (tid < 256 && tid >= o) ? stmp[tid - o] : 0;
      __syncthreads();
      x += y;
      if (tid < 256) stmp[tid] = x;
      __syncthreads();
    }
    int base = (b == 0) ? 0 : stmp[b - 1];   // exclusive prefix (stmp inclusive)
    if (b == 0 && tid == 0) off[2 * N_NODES] = stmp[NBINS - 1];  // total == 2E
    int n = min(bincnt[b], BIN_CAP);

    sh[tid] = 0;
    __syncthreads();
    for (int t = tid; t < n; t += 512) {
      int row = binbuf[(size_t)b * BIN_CAP + t].x;
      atomicAdd(&sh[row & (BIN_ROWS - 1)], 1);
    }
    __syncthreads();
    int v = sh[tid];
    int xx = v;
    for (int o = 1; o < BIN_ROWS; o <<= 1) {   // validated 512-wide scan
      int y = (tid >= o) ? sh[tid - o] : 0;
      __syncthreads();
      xx += y;
      sh[tid] = xx;
      __syncthreads();
    }
    lp[tid] = xx - v;                           // exclusive local prefix
    int row = (b << BIN_SHIFT) + tid;
    if (row < 2 * N_NODES) off[row] = base + lp[tid];
    __syncthreads();
    sh[tid] = lp[tid];                          // cursors
    __syncthreads();
    for (int t = tid; t < n; t += 512) {
      int2 e = binbuf[(size_t)b * BIN_CAP + t];
      int p = atomicAdd(&sh[e.x & (BIN_ROWS - 1)], 1);
      adj[base + p] = e.y;                      // bin-local contiguous window
    }
    return;
  }

  // ---- gemm64 part: C[M,64] = bf16(A[M,128] @ W[128,64]) ----
  constexpr int BM = 64, BK = 16, BN = 64;
  constexpr int TCOL = BN / 16;  // 4
  const int tx = tid & 15;
  const int ty = (tid >> 4) & 15;               // meaningful for tid<256
  const int row0 = (blockIdx.x - NBINS) * BM;
  float acc[4][TCOL];
#pragma unroll
  for (int r = 0; r < 4; ++r)
#pragma unroll
    for (int c = 0; c < TCOL; ++c) acc[r][c] = 0.f;

  for (int k0 = 0; k0 < D; k0 += BK) {          // uniform trip for all 512 threads
    if (tid < 256) {  // stage A tile transposed: As[k][row]
      int r = tid >> 2;
      int kq = (tid & 3) << 2;
      int gr = row0 + r;
      float4 v = make_float4(0.f, 0.f, 0.f, 0.f);
      if (gr < N_NODES) v = *(const float4*)(A + (size_t)gr * D + k0 + kq);
      As[kq + 0][r] = v.x;
      As[kq + 1][r] = v.y;
      As[kq + 2][r] = v.z;
      As[kq + 3][r] = v.w;
    }
    if (tid < 256) {  // stage W tile: Ws[k][c]
      int k = tid >> 4;
      int c4 = (tid & 15) << 2;
      *(float4*)(&Ws[k][c4]) = *(const float4*)(W + (size_t)(k0 + k) * BN + c4);
    }
    __syncthreads();
    if (tid < 256) {
#pragma unroll
      for (int k = 0; k < BK; ++k) {
        float a[4];
#pragma unroll
        for (int r = 0; r < 4; ++r) a[r] = As[k][ty * 4 + r];
        float w[TCOL];
#pragma unroll
        for (int c = 0; c < TCOL; ++c) w[c] = Ws[k][tx * TCOL + c];
#pragma unroll
        for (int r = 0; r < 4; ++r)
#pragma unroll
          for (int c = 0; c < TCOL; ++c) acc[r][c] += a[r] * w[c];
      }
    }
    __syncthreads();
  }
  if (tid < 256) {
#pragma unroll
    for (int r = 0; r < 4; ++r) {
      int gr = row0 + ty * 4 + r;
      if (gr < N_NODES) {
        ushort4 pk;
        pk.x = f2bf(acc[r][0]);
        pk.y = f2bf(acc[r][1]);
        pk.z = f2bf(acc[r][2]);
        pk.w = f2bf(acc[r][3]);
        *(ushort4*)(C + (size_t)gr * BN + tx * TCOL) = pk;
      }
    }
  }
}

// ============ 64-wide aggregation over bf16 table (validated + 4-deep unroll; CONTROL) ============
// FIN: Y += 1.7*s(v)*c + 1.7*b2, s(v) = 1.7 + 0.9*deg1 + 0.8*deg2.

template <int FIN, int OUT_BF16>
__global__ __launch_bounds__(256) void agg64_kernel(const unsigned short* __restrict__ X,
                                                    const int* __restrict__ off,
                                                    const int* __restrict__ adj,
                                                    const float* __restrict__ cvec,
                                                    const float* __restrict__ b2,
                                                    void* __restrict__ Yv) {
  int wid = (blockIdx.x * blockDim.x + threadIdx.x) >> 6;  // node
  if (wid >= N_NODES) return;
  int lane = threadIdx.x & 63;

  float self = bf2f(X[(size_t)wid * 64 + lane]);

  int s1 = off[wid], e1 = off[wid + 1];
  int s2 = off[N_NODES + wid], e2 = off[N_NODES + wid + 1];

  float acc[2];
#pragma unroll
  for (int g = 0; g < 2; ++g) {
    int s = g ? s2 : s1, e = g ? e2 : e1;
    float a0 = 0.f, a1 = 0.f, a2 = 0.f, a3 = 0.f;
    for (int base = s; base < e; base += 64) {
      int m = e - base;
      if (m > 64) m = 64;
      int idx = (lane < m) ? adj[base + lane] : 0;  // coalesced index batch
      int i = 0;
      for (; i + 4 <= m; i += 4) {                  // uniform trip, 4 loads in flight
        int n0 = __shfl(idx, i + 0);
        int n1 = __shfl(idx, i + 1);
        int n2 = __shfl(idx, i + 2);
        int n3 = __shfl(idx, i + 3);
        float f0 = bf2f(X[(size_t)n0 * 64 + lane]);
        float f1 = bf2f(X[(size_t)n1 * 64 + lane]);
        float f2 = bf2f(X[(size_t)n2 * 64 + lane]);
        float f3 = bf2f(X[(size_t)n3 * 64 + lane]);
        a0 += f0; a1 += f1; a2 += f2; a3 += f3;
      }
      for (; i < m; ++i) {                          // uniform tail
        int n0 = __shfl(idx, i);
        a0 += bf2f(X[(size_t)n0 * 64 + lane]);
      }
    }
    acc[g] = (a0 + a1) + (a2 + a3);
  }
  float y = 1.7f * self + 0.9f * acc[0] + 0.8f * acc[1];
  if (FIN) {
    float sv = 1.7f * (1.7f + 0.9f * (float)(e1 - s1) + 0.8f * (float)(e2 - s2));
    y += sv * cvec[lane] + 1.7f * b2[lane];
  }
  if (OUT_BF16) {
    ((unsigned short*)Yv)[(size_t)wid * 64 + lane] = f2bf(y);
  } else {
    ((float*)Yv)[(size_t)wid * 64 + lane] = y;
  }
}

// ============ launch ============
// Math: gates == 1 (softmax over size-1 axis), so with L(X) = 1.7X + 0.9*A1X + 0.8*A2X:
//   out = L(L(F @ W12)) + 1.7*s(v)*(b1@W2) + 1.7*b2    (pushdown exact; validated R5)
// 5 dispatches: memset -> scatter+w12 -> bin_build+gemm -> agg -> agg.

extern "C" void kernel_launch(void* const* d_in, const int* in_sizes, int n_in,
                              void* d_out, int out_size, void* d_ws, size_t ws_size,
                              hipStream_t stream) {
  const float* F  = (const float*)d_in[0];
  const int* src1 = (const int*)d_in[1];
  const int* dst1 = (const int*)d_in[2];
  const int* src2 = (const int*)d_in[3];
  const int* dst2 = (const int*)d_in[4];
  const float* W1 = (const float*)d_in[5];
  const float* b1 = (const float*)d_in[6];
  const float* W2 = (const float*)d_in[7];
  const float* b2 = (const float*)d_in[8];
  // d_in[9..16] (gate weights) are dead: softmax over a size-1 axis == 1.
  float* out = (float*)d_out;

  char* ws = (char*)d_ws;
  auto aln = [](size_t x) { return (x + 255) & ~(size_t)255; };
  size_t o = 0;
  int* bincnt  = (int*)(ws + o); o = aln(o + (size_t)NBINS * 4);
  int* off     = (int*)(ws + o); o = aln(o + ((size_t)2 * N_NODES + 1) * 4);
  int2* binbuf = (int2*)(ws + o); o = aln(o + (size_t)NBINS * BIN_CAP * 8);
  int* adj     = (int*)(ws + o); o = aln(o + (size_t)2 * N_EDGES * 4);
  float* W12   = (float*)(ws + o); o = aln(o + (size_t)D * NCLS * 4);
  float* cvec  = (float*)(ws + o); o = aln(o + NCLS * 4);
  unsigned short* H = (unsigned short*)(ws + o); o = aln(o + (size_t)N_NODES * NCLS * 2);
  unsigned short* T = (unsigned short*)(ws + o); o = aln(o + (size_t)N_NODES * NCLS * 2);
  (void)ws_size;  // ~31 MB used

  hipMemsetAsync(bincnt, 0, (size_t)NBINS * 4, stream);
  // K1: scatter into bins + W12/cvec
  scatter_w12<<<NCHUNKS + W12_BLOCKS, 256, 0, stream>>>(src1, dst1, src2, dst2,
                                                        bincnt, binbuf, W1, W2, b1, W12, cvec);
  // K2: per-bin CSR build (off, adj) + H = bf16(F @ W12)
  build_gemm<<<NBINS + (N_NODES + 63) / 64, 512, 0, stream>>>(bincnt, binbuf, off, adj,
                                                              F, W12, H);
  // T = bf16(L(H))
  agg64_kernel<0, 1><<<N_NODES / 4, 256, 0, stream>>>(H, off, adj, cvec, b2, T);
  // out = L(T) + 1.7*s(v)*c + 1.7*b2   (f32)
  agg64_kernel<1, 0><<<N_NODES / 4, 256, 0, stream>>>(T, off, adj, cvec, b2, out);
}

// Round 13
// 206.066 us; speedup vs baseline: 2.3121x; 1.0249x over previous
//
#include <hip/hip_runtime.h>

#define N_NODES 50000
#define N_EDGES 600000
#define D 128   // D_IN == HID
#define NCLS 64

// Binned CSR build over INTERLEAVED row space: row(v,g) = 2v+g, rows 0..2N-1.
// A node's two graph ranges are adjacent: [off[2v],off[2v+1]) u [off[2v+1],off[2v+2]).
#define BIN_SHIFT 9
#define BIN_ROWS 512
#define NBINS 196        // ceil(100000/512)
#define BIN_CAP 8192     // mean 6122, sd 78 -> +26 sigma
#define CHUNK 4096       // edges per multisplit block
#define EPT (CHUNK / 256)
#define NCHUNKS 293      // ceil(2E/CHUNK)
#define W12_BLOCKS 17    // 17*256 = 4352 threads for 8256 outputs

// bf16 helpers (tables only; all arithmetic stays f32)
__device__ inline unsigned short f2bf(float f) {
  unsigned int u = __float_as_uint(f);
  unsigned int r = (u + 0x7FFF + ((u >> 16) & 1)) >> 16;  // RNE
  return (unsigned short)r;
}
__device__ inline float bf2f(unsigned short b) {
  return __uint_as_float(((unsigned int)b) << 16);
}

// ============ K1: multisplit scatter (blocks < NCHUNKS) + W12/cvec (blocks >= NCHUNKS) ============

__global__ __launch_bounds__(256) void scatter_w12(const int* __restrict__ src1,
                                                   const int* __restrict__ dst1,
                                                   const int* __restrict__ src2,
                                                   const int* __restrict__ dst2,
                                                   int* __restrict__ bincnt,
                                                   int2* __restrict__ binbuf,
                                                   const float* __restrict__ W1,
                                                   const float* __restrict__ W2,
                                                   const float* __restrict__ b1,
                                                   float* __restrict__ W12,
                                                   float* __restrict__ cvec) {
  __shared__ int bcnt[NBINS];
  __shared__ int boff[NBINS];
  __shared__ int gbase[NBINS];
  __shared__ int stmp[256];
  __shared__ int2 stage[CHUNK];

  if (blockIdx.x >= NCHUNKS) {  // ---- w12 part: W12 = W1@W2, cvec = b1@W2 ----
    int gid = (blockIdx.x - NCHUNKS) * 256 + threadIdx.x;
    for (int t = gid; t < D * NCLS + NCLS; t += W12_BLOCKS * 256) {
      if (t < D * NCLS) {
        int i = t >> 6, j = t & 63;
        float s = 0.f;
        for (int k = 0; k < D; ++k) s += W1[i * D + k] * W2[k * NCLS + j];
        W12[t] = s;
      } else {
        int j = t - D * NCLS;
        float s = 0.f;
        for (int k = 0; k < D; ++k) s += b1[k] * W2[k * NCLS + j];
        cvec[j] = s;
      }
    }
    return;
  }

  int base = blockIdx.x * CHUNK;
  int nloc = min(CHUNK, 2 * N_EDGES - base);

  for (int t = threadIdx.x; t < NBINS; t += 256) bcnt[t] = 0;
  __syncthreads();

  int rows[EPT], srcs[EPT], bins[EPT];
#pragma unroll
  for (int k = 0; k < EPT; ++k) {
    int t = threadIdx.x + k * 256;  // coalesced
    rows[k] = -1;
    if (t < nloc) {
      int i = base + t;
      int row, sv;
      if (i < N_EDGES) { row = dst1[i] * 2; sv = src1[i]; }            // graph 1 -> even rows
      else { int e = i - N_EDGES; row = dst2[e] * 2 + 1; sv = src2[e]; }  // graph 2 -> odd rows
      rows[k] = row; srcs[k] = sv;
      bins[k] = row >> BIN_SHIFT;
      atomicAdd(&bcnt[bins[k]], 1);
    }
  }
  __syncthreads();
  {  // exclusive scan bcnt -> boff (NBINS <= 256)
    int tid = threadIdx.x;
    int v = (tid < NBINS) ? bcnt[tid] : 0;
    stmp[tid] = v;
    __syncthreads();
    int x = v;
    for (int o = 1; o < 256; o <<= 1) {
      int y = (tid >= o) ? stmp[tid - o] : 0;
      __syncthreads();
      x += y;
      stmp[tid] = x;
      __syncthreads();
    }
    if (tid < NBINS) boff[tid] = x - v;
  }
  __syncthreads();
  for (int t = threadIdx.x; t < NBINS; t += 256) {  // stash count; init cursor
    gbase[t] = bcnt[t];
    bcnt[t] = boff[t];
  }
  __syncthreads();
#pragma unroll
  for (int k = 0; k < EPT; ++k) {  // rank + place into bin-grouped LDS
    if (rows[k] >= 0) {
      int p = atomicAdd(&bcnt[bins[k]], 1);
      stage[p] = make_int2(rows[k], srcs[k]);
    }
  }
  __syncthreads();
  for (int t = threadIdx.x; t < NBINS; t += 256) {  // one global atomic per bin
    int c = gbase[t];
    if (c > 0) gbase[t] = atomicAdd(&bincnt[t], c);
  }
  __syncthreads();
  for (int j = threadIdx.x; j < nloc; j += 256) {  // flush contiguous runs
    int2 e = stage[j];
    int b = e.x >> BIN_SHIFT;
    int gp = gbase[b] + (j - boff[b]);
    if (gp < BIN_CAP) binbuf[(size_t)b * BIN_CAP + gp] = e;
  }
}

// ============ K2: bin_build (blocks < NBINS) + gemm64 (blocks >= NBINS), 512 threads ============
// (row-space agnostic; unchanged from HW-validated R9/R10 version)

__global__ __launch_bounds__(512) void build_gemm(const int* __restrict__ bincnt,
                                                  const int2* __restrict__ binbuf,
                                                  int* __restrict__ off, int* __restrict__ adj,
                                                  const float* __restrict__ A,
                                                  const float* __restrict__ W,
                                                  unsigned short* __restrict__ C) {
  __shared__ int sh[BIN_ROWS];
  __shared__ int lp[BIN_ROWS];
  __shared__ int stmp[256];
  __shared__ float As[16][65];
  __shared__ float Ws[16][64];

  int tid = threadIdx.x;

  if (blockIdx.x < NBINS) {  // ---- bin_build part ----
    int b = blockIdx.x;
    if (tid < 256) stmp[tid] = (tid < NBINS) ? bincnt[tid] : 0;
    __syncthreads();
    int x = (tid < 256) ? stmp[tid] : 0;
    for (int o = 1; o < 256; o <<= 1) {
      int y = (tid < 256 && tid >= o) ? stmp[tid - o] : 0;
      __syncthreads();
      x += y;
      if (tid < 256) stmp[tid] = x;
      __syncthreads();
    }
    int base = (b == 0) ? 0 : stmp[b - 1];   // exclusive prefix (stmp inclusive)
    if (b == 0 && tid == 0) off[2 * N_NODES] = stmp[NBINS - 1];  // total == 2E
    int n = min(bincnt[b], BIN_CAP);

    sh[tid] = 0;
    __syncthreads();
    for (int t = tid; t < n; t += 512) {
      int row = binbuf[(size_t)b * BIN_CAP + t].x;
      atomicAdd(&sh[row & (BIN_ROWS - 1)], 1);
    }
    __syncthreads();
    int v = sh[tid];
    int xx = v;
    for (int o = 1; o < BIN_ROWS; o <<= 1) {   // validated 512-wide scan
      int y = (tid >= o) ? sh[tid - o] : 0;
      __syncthreads();
      xx += y;
      sh[tid] = xx;
      __syncthreads();
    }
    lp[tid] = xx - v;                           // exclusive local prefix
    int row = (b << BIN_SHIFT) + tid;
    if (row < 2 * N_NODES) off[row] = base + lp[tid];
    __syncthreads();
    sh[tid] = lp[tid];                          // cursors
    __syncthreads();
    for (int t = tid; t < n; t += 512) {
      int2 e = binbuf[(size_t)b * BIN_CAP + t];
      int p = atomicAdd(&sh[e.x & (BIN_ROWS - 1)], 1);
      adj[base + p] = e.y;                      // bin-local contiguous window
    }
    return;
  }

  // ---- gemm64 part: C[M,64] = bf16(A[M,128] @ W[128,64]) ----
  constexpr int BM = 64, BK = 16, BN = 64;
  constexpr int TCOL = BN / 16;  // 4
  const int tx = tid & 15;
  const int ty = (tid >> 4) & 15;
  const int row0 = (blockIdx.x - NBINS) * BM;
  float acc[4][TCOL];
#pragma unroll
  for (int r = 0; r < 4; ++r)
#pragma unroll
    for (int c = 0; c < TCOL; ++c) acc[r][c] = 0.f;

  for (int k0 = 0; k0 < D; k0 += BK) {          // uniform trip for all 512 threads
    if (tid < 256) {  // stage A tile transposed: As[k][row]
      int r = tid >> 2;
      int kq = (tid & 3) << 2;
      int gr = row0 + r;
      float4 v = make_float4(0.f, 0.f, 0.f, 0.f);
      if (gr < N_NODES) v = *(const float4*)(A + (size_t)gr * D + k0 + kq);
      As[kq + 0][r] = v.x;
      As[kq + 1][r] = v.y;
      As[kq + 2][r] = v.z;
      As[kq + 3][r] = v.w;
    }
    if (tid < 256) {  // stage W tile: Ws[k][c]
      int k = tid >> 4;
      int c4 = (tid & 15) << 2;
      *(float4*)(&Ws[k][c4]) = *(const float4*)(W + (size_t)(k0 + k) * BN + c4);
    }
    __syncthreads();
    if (tid < 256) {
#pragma unroll
      for (int k = 0; k < BK; ++k) {
        float a[4];
#pragma unroll
        for (int r = 0; r < 4; ++r) a[r] = As[k][ty * 4 + r];
        float w[TCOL];
#pragma unroll
        for (int c = 0; c < TCOL; ++c) w[c] = Ws[k][tx * TCOL + c];
#pragma unroll
        for (int r = 0; r < 4; ++r)
#pragma unroll
          for (int c = 0; c < TCOL; ++c) acc[r][c] += a[r] * w[c];
      }
    }
    __syncthreads();
  }
  if (tid < 256) {
#pragma unroll
    for (int r = 0; r < 4; ++r) {
      int gr = row0 + ty * 4 + r;
      if (gr < N_NODES) {
        ushort4 pk;
        pk.x = f2bf(acc[r][0]);
        pk.y = f2bf(acc[r][1]);
        pk.z = f2bf(acc[r][2]);
        pk.w = f2bf(acc[r][3]);
        *(ushort4*)(C + (size_t)gr * BN + tx * TCOL) = pk;
      }
    }
  }
}

// ============ 64-wide aggregation, merged ranges + 8-deep unroll ============
// Node v: s=off[2v], mid=off[2v+1], e=off[2v+2]. One loop over [s,e) with
// wave-uniform per-edge weight (base+i<mid ? 0.9 : 0.8). 8 loads in flight.
// FIN: Y += 1.7*s(v)*c + 1.7*b2, s(v) = 1.7 + 0.9*deg1 + 0.8*deg2.

template <int FIN, int OUT_BF16>
__global__ __launch_bounds__(256) void agg64_kernel(const unsigned short* __restrict__ X,
                                                    const int* __restrict__ off,
                                                    const int* __restrict__ adj,
                                                    const float* __restrict__ cvec,
                                                    const float* __restrict__ b2,
                                                    void* __restrict__ Yv) {
  int wid = (blockIdx.x * blockDim.x + threadIdx.x) >> 6;  // node
  if (wid >= N_NODES) return;
  int lane = threadIdx.x & 63;

  float self = bf2f(X[(size_t)wid * 64 + lane]);

  int s = off[2 * wid], mid = off[2 * wid + 1], e = off[2 * wid + 2];

  float a0 = 0.f, a1 = 0.f, a2 = 0.f, a3 = 0.f;
  float a4 = 0.f, a5 = 0.f, a6 = 0.f, a7 = 0.f;
  for (int base = s; base < e; base += 64) {
    int m = e - base;
    if (m > 64) m = 64;
    int idx = (lane < m) ? adj[base + lane] : 0;  // coalesced index batch
    int i = 0;
    for (; i + 8 <= m; i += 8) {                  // uniform trip, 8 loads in flight
      int n0 = __shfl(idx, i + 0);
      int n1 = __shfl(idx, i + 1);
      int n2 = __shfl(idx, i + 2);
      int n3 = __shfl(idx, i + 3);
      int n4 = __shfl(idx, i + 4);
      int n5 = __shfl(idx, i + 5);
      int n6 = __shfl(idx, i + 6);
      int n7 = __shfl(idx, i + 7);
      float w0 = (base + i + 0 < mid) ? 0.9f : 0.8f;   // wave-uniform
      float w1 = (base + i + 1 < mid) ? 0.9f : 0.8f;
      float w2 = (base + i + 2 < mid) ? 0.9f : 0.8f;
      float w3 = (base + i + 3 < mid) ? 0.9f : 0.8f;
      float w4 = (base + i + 4 < mid) ? 0.9f : 0.8f;
      float w5 = (base + i + 5 < mid) ? 0.9f : 0.8f;
      float w6 = (base + i + 6 < mid) ? 0.9f : 0.8f;
      float w7 = (base + i + 7 < mid) ? 0.9f : 0.8f;
      a0 += w0 * bf2f(X[(size_t)n0 * 64 + lane]);
      a1 += w1 * bf2f(X[(size_t)n1 * 64 + lane]);
      a2 += w2 * bf2f(X[(size_t)n2 * 64 + lane]);
      a3 += w3 * bf2f(X[(size_t)n3 * 64 + lane]);
      a4 += w4 * bf2f(X[(size_t)n4 * 64 + lane]);
      a5 += w5 * bf2f(X[(size_t)n5 * 64 + lane]);
      a6 += w6 * bf2f(X[(size_t)n6 * 64 + lane]);
      a7 += w7 * bf2f(X[(size_t)n7 * 64 + lane]);
    }
    for (; i < m; ++i) {                          // uniform tail
      int n0 = __shfl(idx, i);
      float w = (base + i < mid) ? 0.9f : 0.8f;
      a0 += w * bf2f(X[(size_t)n0 * 64 + lane]);
    }
  }
  float acc = ((a0 + a1) + (a2 + a3)) + ((a4 + a5) + (a6 + a7));
  float y = 1.7f * self + acc;
  if (FIN) {
    float sv = 1.7f * (1.7f + 0.9f * (float)(mid - s) + 0.8f * (float)(e - mid));
    y += sv * cvec[lane] + 1.7f * b2[lane];
  }
  if (OUT_BF16) {
    ((unsigned short*)Yv)[(size_t)wid * 64 + lane] = f2bf(y);
  } else {
    ((float*)Yv)[(size_t)wid * 64 + lane] = y;
  }
}

// ============ launch ============
// Math: gates == 1 (softmax over size-1 axis), so with L(X) = 1.7X + 0.9*A1X + 0.8*A2X:
//   out = L(L(F @ W12)) + 1.7*s(v)*(b1@W2) + 1.7*b2    (pushdown exact; validated R5)
// 5 dispatches: memset -> scatter+w12 -> bin_build+gemm -> agg -> agg.

extern "C" void kernel_launch(void* const* d_in, const int* in_sizes, int n_in,
                              void* d_out, int out_size, void* d_ws, size_t ws_size,
                              hipStream_t stream) {
  const float* F  = (const float*)d_in[0];
  const int* src1 = (const int*)d_in[1];
  const int* dst1 = (const int*)d_in[2];
  const int* src2 = (const int*)d_in[3];
  const int* dst2 = (const int*)d_in[4];
  const float* W1 = (const float*)d_in[5];
  const float* b1 = (const float*)d_in[6];
  const float* W2 = (const float*)d_in[7];
  const float* b2 = (const float*)d_in[8];
  // d_in[9..16] (gate weights) are dead: softmax over a size-1 axis == 1.
  float* out = (float*)d_out;

  char* ws = (char*)d_ws;
  auto aln = [](size_t x) { return (x + 255) & ~(size_t)255; };
  size_t o = 0;
  int* bincnt  = (int*)(ws + o); o = aln(o + (size_t)NBINS * 4);
  int* off     = (int*)(ws + o); o = aln(o + ((size_t)2 * N_NODES + 1) * 4);
  int2* binbuf = (int2*)(ws + o); o = aln(o + (size_t)NBINS * BIN_CAP * 8);
  int* adj     = (int*)(ws + o); o = aln(o + (size_t)2 * N_EDGES * 4);
  float* W12   = (float*)(ws + o); o = aln(o + (size_t)D * NCLS * 4);
  float* cvec  = (float*)(ws + o); o = aln(o + NCLS * 4);
  unsigned short* H = (unsigned short*)(ws + o); o = aln(o + (size_t)N_NODES * NCLS * 2);
  unsigned short* T = (unsigned short*)(ws + o); o = aln(o + (size_t)N_NODES * NCLS * 2);
  (void)ws_size;  // ~31 MB used

  hipMemsetAsync(bincnt, 0, (size_t)NBINS * 4, stream);
  // K1: scatter into bins (interleaved rows) + W12/cvec
  scatter_w12<<<NCHUNKS + W12_BLOCKS, 256, 0, stream>>>(src1, dst1, src2, dst2,
                                                        bincnt, binbuf, W1, W2, b1, W12, cvec);
  // K2: per-bin CSR build (off, adj) + H = bf16(F @ W12)
  build_gemm<<<NBINS + (N_NODES + 63) / 64, 512, 0, stream>>>(bincnt, binbuf, off, adj,
                                                              F, W12, H);
  // T = bf16(L(H))
  agg64_kernel<0, 1><<<N_NODES / 4, 256, 0, stream>>>(H, off, adj, cvec, b2, T);
  // out = L(T) + 1.7*s(v)*c + 1.7*b2   (f32)
  agg64_kernel<1, 0><<<N_NODES / 4, 256, 0, stream>>>(T, off, adj, cvec, b2, out);
}